// Round 8
// baseline (293.960 us; speedup 1.0000x reference)
//
#include <hip/hip_runtime.h>
#include <hip/hip_cooperative_groups.h>
#include <math.h>
#include <stdint.h>

namespace cg = cooperative_groups;

namespace {
constexpr int B = 32, Q = 48, A = 48, D = 300;
constexpr int C = 512, K = 5, H = 512, P = 512, NCLS = 2;
constexpr int CK = C * K;         // 2560
constexpr int M = B * Q;          // 1536
constexpr int KP = 320;           // K padded for bf16 MFMA
constexpr float EPS_COS = 1e-6f, EPS_BN = 1e-5f;
constexpr int NCVT = (2 * (M + CK) * 40) / 256;      // 1280 virtual blocks
constexpr int NTPJ = (3 * H / 32) * (P / 32);        // 768  (proj_w transpose)
constexpr int NTPF = (H / 32) * (C / 32);            // 256  (each fc weight)
constexpr int NCOS = M / 4;                          // 384
constexpr int NPREP = NCVT + NTPJ + 2 * NTPF + NCOS; // 2944
constexpr int GRID = 256;                            // 1 block/CU (84.5KB LDS)
}
using short8 = __attribute__((ext_vector_type(8))) short;
using f32x4  = __attribute__((ext_vector_type(4))) float;

__device__ inline short f2bf(float v) {
  uint32_t u = __builtin_bit_cast(uint32_t, v);
  return (short)((u + 0x7fffu + ((u >> 16) & 1u)) >> 16);  // RNE
}

struct Args {
  const float *q, *a, *smw, *smbias, *smfcw, *smfcb;
  const float *ctxw, *ctxbias, *ctxfcw, *ctxfcb;
  const float *projw, *projb, *gamma, *beta, *outw, *outb;
  short *qb, *ab, *smb, *ctxb;
  float *projT, *smfcwT, *ctxfcwT, *cosm;
  float *pooled, *pbar, *acnn, *bcnn, *attnf, *comb, *tbuf;
  float *out;
};

__global__ void __launch_bounds__(256) mega_k(Args Ar) {
  __shared__ __align__(16) char Lraw[84480];
  cg::grid_group grid = cg::this_grid();
  const int tid = threadIdx.x;

  // ============================ phase 0: prep ==============================
  {
    float (*tile)[33] = (float (*)[33])Lraw;          // 4224 B
    float4* qrow4 = (float4*)(Lraw + 4352);           // 4800 B
    for (int vb = blockIdx.x; vb < NPREP; vb += GRID) {
      __syncthreads();  // protect LDS reuse across iterations
      if (vb < NCVT) {
        const int idx = vb * 256 + tid;
        const int row = idx / 40, ch = idx - row * 40;
        const float* src; short* dst; int r;
        if (row < M)              { src = Ar.q;    dst = Ar.qb;   r = row; }
        else if (row < 2 * M)     { src = Ar.a;    dst = Ar.ab;   r = row - M; }
        else if (row < 2 * M + CK){ src = Ar.smw;  dst = Ar.smb;  r = row - 2 * M; }
        else                      { src = Ar.ctxw; dst = Ar.ctxb; r = row - 2 * M - CK; }
        short tmp[8];
#pragma unroll
        for (int e = 0; e < 8; ++e) {
          const int k = ch * 8 + e;
          tmp[e] = (k < D) ? f2bf(src[(size_t)r * D + k]) : (short)0;
        }
        *(int4*)&dst[(size_t)r * KP + ch * 8] = *(const int4*)tmp;
      } else if (vb < NCVT + NTPJ) {
        const int b2 = vb - NCVT;
        const int j0 = (b2 % 48) * 32, p0 = (b2 / 48) * 32;
        const int tx = tid & 31, ty = tid >> 5;
        for (int i = ty; i < 32; i += 8)
          tile[i][tx] = Ar.projw[(size_t)(p0 + i) * (3 * H) + j0 + tx];
        __syncthreads();
        for (int i = ty; i < 32; i += 8)
          Ar.projT[(size_t)(j0 + i) * P + p0 + tx] = tile[tx][i];
      } else if (vb < NCVT + NTPJ + 2 * NTPF) {
        const int b3 = vb - NCVT - NTPJ;
        const bool isCtx = b3 >= NTPF;
        const int b4 = isCtx ? b3 - NTPF : b3;
        const float* W = isCtx ? Ar.ctxfcw : Ar.smfcw;
        float* WT = isCtx ? Ar.ctxfcwT : Ar.smfcwT;
        const int c0 = (b4 % 16) * 32, h0 = (b4 / 16) * 32;
        const int tx = tid & 31, ty = tid >> 5;
        for (int i = ty; i < 32; i += 8)
          tile[i][tx] = W[(size_t)(h0 + i) * C + c0 + tx];
        __syncthreads();
        for (int i = ty; i < 32; i += 8)
          WT[(size_t)(c0 + i) * H + h0 + tx] = tile[tx][i];
      } else {
        const int b5 = vb - NCVT - NTPJ - 2 * NTPF;
        const int qq = b5 * 4;            // 4 q-rows, same b (48 % 4 == 0)
        const int b = qq / Q;
        const float4* qp4 = (const float4*)(Ar.q + (size_t)qq * D);
        for (int i = tid; i < 300; i += 256) qrow4[i] = qp4[i];
        __syncthreads();
        const int sub = tid >> 6, lane = tid & 63;
        float qsq = 0.f;
        for (int i = lane; i < 75; i += 64) {
          float4 v = qrow4[sub * 75 + i];
          qsq += v.x * v.x + v.y * v.y + v.z * v.z + v.w * v.w;
        }
#pragma unroll
        for (int off2 = 32; off2; off2 >>= 1) qsq += __shfl_xor(qsq, off2);
        const float qn = sqrtf(qsq);
        if (lane < A) {
          const float4* ap4 = (const float4*)(Ar.a + ((size_t)b * A + lane) * D);
          float dot = 0.f, asq = 0.f;
          for (int i = 0; i < 75; ++i) {
            float4 av = ap4[i], qv = qrow4[sub * 75 + i];
            dot += qv.x * av.x + qv.y * av.y + qv.z * av.z + qv.w * av.w;
            asq += av.x * av.x + av.y * av.y + av.z * av.z + av.w * av.w;
          }
          Ar.cosm[(size_t)(qq + sub) * A + lane] = dot / fmaxf(qn * sqrtf(asq), EPS_COS);
        }
      }
    }
  }
  grid.sync();

  // ================= phase 1: fused GEMM + pooling (sm & ctx) ==============
  {
    float (*Sl)[56][80] = (float (*)[56][80])Lraw;      // 71680 B
    float (*cosl)[56]   = (float (*)[56])(Lraw + 71680);// 10752 B
    float* redf         = (float*)(Lraw + 82432);       // 2048 B
    const int lane = tid & 63, wv = tid >> 6;
    const int r16 = lane & 15, kq = lane >> 4;

    for (int vb = blockIdx.x; vb < 768; vb += GRID) {
      __syncthreads();  // prior iteration's pool reads done before overwrite
      const bool isSm = vb < 512;
      const int v2 = isSm ? vb : vb - 512;
      const int nb = v2 >> 3, cgi = v2 & 7;   // sm: nb=0..63; ctx: nb=b=0..31
      const short* X = isSm
          ? ((nb < B) ? Ar.qb + (size_t)nb * 48 * KP : Ar.ab + (size_t)(nb - B) * 48 * KP)
          : Ar.ab + (size_t)nb * 48 * KP;
      const short* Wm = isSm ? Ar.smb : Ar.ctxb;
      const int gc0 = cgi * 320 + wv * 80;
      const short* Xw = X + (size_t)r16 * KP + kq * 8;
      const short* Wt = Wm + (size_t)(gc0 + r16) * KP + kq * 8;

      for (int i = lane; i < 640; i += 64) {  // zero pad rows 0..3, 52..55
        const int rr = i / 80, cc2 = i % 80;
        Sl[wv][rr < 4 ? rr : rr + 48][cc2] = 0.f;
      }
      if (!isSm) {  // stage cos rows, zero-padded position axis
        for (int i = tid; i < 48 * 56; i += 256) {
          const int qi = i / 56, p4 = i % 56;
          cosl[qi][p4] = (p4 >= 4 && p4 < 52)
                       ? Ar.cosm[((size_t)nb * Q + qi) * A + p4 - 4] : 0.f;
        }
      }

      f32x4 acc[3][5];
#pragma unroll
      for (int mi = 0; mi < 3; ++mi)
#pragma unroll
        for (int ni = 0; ni < 5; ++ni) acc[mi][ni] = f32x4{0.f, 0.f, 0.f, 0.f};
      int4 cA[3], cB[5];
#pragma unroll
      for (int i = 0; i < 3; ++i) cA[i] = *(const int4*)(Xw + i * 16 * KP);
#pragma unroll
      for (int i = 0; i < 5; ++i) cB[i] = *(const int4*)(Wt + i * 16 * KP);
#pragma unroll 1
      for (int ks = 0; ks < KP / 32; ++ks) {
        int4 nA[3], nB[5];
        if (ks < KP / 32 - 1) {
#pragma unroll
          for (int i = 0; i < 3; ++i) nA[i] = *(const int4*)(Xw + i * 16 * KP + (ks + 1) * 32);
#pragma unroll
          for (int i = 0; i < 5; ++i) nB[i] = *(const int4*)(Wt + i * 16 * KP + (ks + 1) * 32);
        }
#pragma unroll
        for (int mi = 0; mi < 3; ++mi)
#pragma unroll
          for (int ni = 0; ni < 5; ++ni)
            acc[mi][ni] = __builtin_amdgcn_mfma_f32_16x16x32_bf16(
                __builtin_bit_cast(short8, cA[mi]),
                __builtin_bit_cast(short8, cB[ni]), acc[mi][ni], 0, 0, 0);
        if (ks < KP / 32 - 1) {
#pragma unroll
          for (int i = 0; i < 3; ++i) cA[i] = nA[i];
#pragma unroll
          for (int i = 0; i < 5; ++i) cB[i] = nB[i];
        }
      }
#pragma unroll
      for (int mi = 0; mi < 3; ++mi)
#pragma unroll
        for (int ni = 0; ni < 5; ++ni)
#pragma unroll
          for (int r = 0; r < 4; ++r)
            Sl[wv][mi * 16 + kq * 4 + r + 4][ni * 16 + r16] = acc[mi][ni][r];
      __syncthreads();

      if (isSm) {
        const int ch = tid & 63, part = tid >> 6;
        const int w2 = ch >> 4, cl = (ch & 15) * 5;
        float best = -1e30f;
#pragma unroll
        for (int j = 0; j < 13; ++j) {
          const int l = part * 13 + j;
          const float z = Sl[w2][l + 0][cl + 0] + Sl[w2][l + 1][cl + 1]
                        + Sl[w2][l + 2][cl + 2] + Sl[w2][l + 3][cl + 3]
                        + Sl[w2][l + 4][cl + 4];
          best = fmaxf(best, z);
        }
        redf[part * 64 + ch] = best;
        __syncthreads();
        if (tid < 64) {
          const float m = fmaxf(fmaxf(redf[tid], redf[64 + tid]),
                                fmaxf(redf[128 + tid], redf[192 + tid]));
          Ar.pooled[(size_t)nb * C + cgi * 64 + tid] =
              fmaxf(m + Ar.smbias[cgi * 64 + tid], 0.f);
        }
      } else {
        const int clane = tid & 31, grp = tid >> 5;
        float best[2][6];
#pragma unroll
        for (int cc = 0; cc < 2; ++cc)
#pragma unroll
          for (int j = 0; j < 6; ++j) best[cc][j] = -1e30f;
        for (int ch13 = 0; ch13 < 13; ++ch13) {
          float cw[6][8];
#pragma unroll
          for (int j = 0; j < 6; ++j) {
            const float4 a0 = *(const float4*)&cosl[grp * 6 + j][4 * ch13];
            const float4 a1 = *(const float4*)&cosl[grp * 6 + j][4 * ch13 + 4];
            cw[j][0] = a0.x; cw[j][1] = a0.y; cw[j][2] = a0.z; cw[j][3] = a0.w;
            cw[j][4] = a1.x; cw[j][5] = a1.y; cw[j][6] = a1.z; cw[j][7] = a1.w;
          }
#pragma unroll
          for (int cc = 0; cc < 2; ++cc) {
            const int ch = cc * 32 + clane;
            const int w2 = ch >> 4, cl = (ch & 15) * 5;
            float sk[4][5];
#pragma unroll
            for (int p = 0; p < 4; ++p)
#pragma unroll
              for (int k = 0; k < K; ++k)
                sk[p][k] = Sl[w2][4 * ch13 + p + k][cl + k];
#pragma unroll
            for (int p = 0; p < 4; ++p)
#pragma unroll
              for (int j = 0; j < 6; ++j) {
                float zv = 0.f;
#pragma unroll
                for (int k = 0; k < K; ++k) zv += cw[j][p + k] * sk[p][k];
                best[cc][j] = fmaxf(best[cc][j], zv);
              }
          }
        }
#pragma unroll
        for (int cc = 0; cc < 2; ++cc) {
          const float bc = Ar.ctxbias[cgi * 64 + cc * 32 + clane];
          float s = 0.f;
#pragma unroll
          for (int j = 0; j < 6; ++j) s += fmaxf(best[cc][j] + bc, 0.f);
          redf[cc * 256 + grp * 32 + clane] = s;
        }
        __syncthreads();
        if (tid < 64) {
          const int cc = tid >> 5, cl2 = tid & 31;
          float tot = 0.f;
#pragma unroll
          for (int g = 0; g < 8; ++g) tot += redf[cc * 256 + g * 32 + cl2];
          Ar.pbar[(size_t)nb * C + cgi * 64 + cc * 32 + cl2] = tot * (1.0f / Q);
        }
      }
    }
  }
  grid.sync();

  // ====================== phase 2a: three FCs (coalesced) ==================
  if (blockIdx.x < 192) {
    const int vb = blockIdx.x;
    const int n = vb / 6, rem = vb % 6, z = rem >> 1, hc = rem & 1;
    const int h = hc * 256 + tid;
    const float* in = (z == 0) ? Ar.pooled + (size_t)n * C
                    : (z == 1) ? Ar.pooled + (size_t)(B + n) * C
                               : Ar.pbar + (size_t)n * C;
    const float* WT = (z == 2) ? Ar.ctxfcwT : Ar.smfcwT;
    const float* bs = (z == 2) ? Ar.ctxfcb : Ar.smfcb;
    float* outp = ((z == 0) ? Ar.acnn : (z == 1) ? Ar.bcnn : Ar.attnf) + (size_t)n * H;
    float acc = bs[h];
    for (int c = 0; c < C; ++c) acc += in[c] * WT[(size_t)c * H + h];
    outp[h] = acc;
  }
  grid.sync();

  // ============================ phase 2b: proj =============================
  if (blockIdx.x < 64) {
    const int b = blockIdx.x >> 1, half = blockIdx.x & 1;
    const int p = half * 256 + tid;
    float acc = Ar.projb[p];
    const float* ar = Ar.acnn + (size_t)b * H;
    const float* br = Ar.bcnn + (size_t)b * H;
    const float* cr = Ar.attnf + (size_t)b * H;
    for (int j = 0; j < H; ++j) acc += ar[j] * Ar.projT[(size_t)j * P + p];
    for (int j = 0; j < H; ++j) acc += br[j] * Ar.projT[(size_t)(H + j) * P + p];
    for (int j = 0; j < H; ++j) acc += cr[j] * Ar.projT[(size_t)(2 * H + j) * P + p];
    Ar.comb[(size_t)b * P + p] = acc;
  }
  grid.sync();

  // ======================= phase 3: batchnorm + tanh =======================
  if (blockIdx.x < 8) {
    float* s1 = (float*)Lraw;        // 256
    float* s2 = s1 + 256;            // 256
    const int pl = tid & 63, rg = tid >> 6;
    const int p = blockIdx.x * 64 + pl;
    float v[8];
#pragma unroll
    for (int i = 0; i < 8; ++i) v[i] = Ar.comb[(size_t)(rg * 8 + i) * P + p];
    float a = 0.f;
#pragma unroll
    for (int i = 0; i < 8; ++i) a += v[i];
    s1[rg * 64 + pl] = a;
    __syncthreads();
    const float mu = (s1[pl] + s1[64 + pl] + s1[128 + pl] + s1[192 + pl]) * (1.0f / B);
    float b2 = 0.f;
#pragma unroll
    for (int i = 0; i < 8; ++i) { const float d = v[i] - mu; b2 += d * d; }
    s2[rg * 64 + pl] = b2;
    __syncthreads();
    const float var = (s2[pl] + s2[64 + pl] + s2[128 + pl] + s2[192 + pl]) * (1.0f / B);
    const float inv = rsqrtf(var + EPS_BN);
    const float g = Ar.gamma[p], be = Ar.beta[p];
#pragma unroll
    for (int i = 0; i < 8; ++i)
      Ar.tbuf[(size_t)(rg * 8 + i) * P + p] = tanhf((v[i] - mu) * inv * g + be);
  }
  grid.sync();

  // ============================ phase 4: out FC ============================
  if (blockIdx.x == 0) {
    const int o = tid >> 2, lane4 = tid & 3;   // 64 outputs x 4 lanes
    const int bb = o >> 1, cl = o & 1;
    float acc = 0.f;
    for (int j = lane4; j < P; j += 4)
      acc += Ar.tbuf[(size_t)bb * P + j] * Ar.outw[cl * P + j];
    acc += __shfl_down(acc, 2, 4);
    acc += __shfl_down(acc, 1, 4);
    if (lane4 == 0) Ar.out[bb * NCLS + cl] = acc + Ar.outb[cl];
  }
}

extern "C" void kernel_launch(void* const* d_in, const int* in_sizes, int n_in,
                              void* d_out, int out_size, void* d_ws, size_t ws_size,
                              hipStream_t stream) {
  Args Aa;
  Aa.q       = (const float*)d_in[0];
  Aa.a       = (const float*)d_in[1];
  Aa.smw     = (const float*)d_in[2];
  Aa.smbias  = (const float*)d_in[3];
  Aa.smfcw   = (const float*)d_in[4];
  Aa.smfcb   = (const float*)d_in[5];
  Aa.ctxw    = (const float*)d_in[6];
  Aa.ctxbias = (const float*)d_in[7];
  Aa.ctxfcw  = (const float*)d_in[8];
  Aa.ctxfcb  = (const float*)d_in[9];
  Aa.projw   = (const float*)d_in[10];
  Aa.projb   = (const float*)d_in[11];
  Aa.gamma   = (const float*)d_in[12];
  Aa.beta    = (const float*)d_in[13];
  Aa.outw    = (const float*)d_in[14];
  Aa.outb    = (const float*)d_in[15];

  float* ws = (float*)d_ws;
  size_t off = 0;
  auto alloc = [&](size_t n) { float* p = ws + off; off += n; return p; };
  Aa.projT   = alloc((size_t)3 * H * P);
  Aa.smfcwT  = alloc((size_t)C * H);
  Aa.ctxfcwT = alloc((size_t)C * H);
  Aa.cosm    = alloc((size_t)B * Q * A);
  Aa.pooled  = alloc((size_t)2 * B * C);
  Aa.pbar    = alloc((size_t)B * C);
  Aa.acnn    = alloc((size_t)B * H);
  Aa.bcnn    = alloc((size_t)B * H);
  Aa.attnf   = alloc((size_t)B * H);
  Aa.comb    = alloc((size_t)B * P);
  Aa.tbuf    = alloc((size_t)B * P);
  Aa.qb      = (short*)alloc((size_t)M * KP / 2);
  Aa.ab      = (short*)alloc((size_t)M * KP / 2);
  Aa.smb     = (short*)alloc((size_t)CK * KP / 2);
  Aa.ctxb    = (short*)alloc((size_t)CK * KP / 2);
  Aa.out     = (float*)d_out;

  void* kargs[] = {(void*)&Aa};
  hipLaunchCooperativeKernel((const void*)mega_k, dim3(GRID), dim3(256),
                             kargs, 0, stream);
}

// Round 9
// 139.154 us; speedup vs baseline: 2.1125x; 2.1125x over previous
//
#include <hip/hip_runtime.h>
#include <math.h>
#include <stdint.h>

namespace {
constexpr int B = 32, Q = 48, A = 48, D = 300;
constexpr int C = 512, K = 5, H = 512, P = 512, NCLS = 2;
constexpr int CK = C * K;         // 2560
constexpr int M = B * Q;          // 1536
constexpr int KP = 320;           // K padded for bf16 MFMA
constexpr float EPS_COS = 1e-6f, EPS_BN = 1e-5f;
constexpr int NCVT = (2 * (M + CK) * 40) / 256;      // 1280 virtual blocks
constexpr int NTPJ = (3 * H / 32) * (P / 32);        // 768  (proj_w transpose)
constexpr int NTPF = (H / 32) * (C / 32);            // 256  (each fc weight)
constexpr int NCOS = M / 4;                          // 384
constexpr int NPREP = NCVT + NTPJ + 2 * NTPF + NCOS; // 2944
}
using short8 = __attribute__((ext_vector_type(8))) short;
using f32x4  = __attribute__((ext_vector_type(4))) float;

__device__ inline short f2bf(float v) {
  uint32_t u = __builtin_bit_cast(uint32_t, v);
  return (short)((u + 0x7fffu + ((u >> 16) & 1u)) >> 16);  // RNE
}

// ---------------------------------------------------------------------------
// prep: fp32->bf16 pad-to-320 | proj_w / fc_w transposes | cosine sim
// ---------------------------------------------------------------------------
__global__ void prep_k(const float* __restrict__ q, const float* __restrict__ a,
                       const float* __restrict__ smw, const float* __restrict__ ctxw,
                       const float* __restrict__ projw, const float* __restrict__ smfcw,
                       const float* __restrict__ ctxfcw,
                       short* __restrict__ qb, short* __restrict__ ab,
                       short* __restrict__ smb, short* __restrict__ ctxb,
                       float* __restrict__ projT, float* __restrict__ smfcwT,
                       float* __restrict__ ctxfcwT, float* __restrict__ cosm) {
  __shared__ float tile[32][33];
  __shared__ float4 qrow4[300];
  const int vb = blockIdx.x, tid = threadIdx.x;
  if (vb < NCVT) {
    const int idx = vb * 256 + tid;
    const int row = idx / 40, ch = idx - row * 40;
    const float* src; short* dst; int r;
    if (row < M)              { src = q;    dst = qb;   r = row; }
    else if (row < 2 * M)     { src = a;    dst = ab;   r = row - M; }
    else if (row < 2 * M + CK){ src = smw;  dst = smb;  r = row - 2 * M; }
    else                      { src = ctxw; dst = ctxb; r = row - 2 * M - CK; }
    short tmp[8];
#pragma unroll
    for (int e = 0; e < 8; ++e) {
      const int k = ch * 8 + e;
      tmp[e] = (k < D) ? f2bf(src[(size_t)r * D + k]) : (short)0;
    }
    *(int4*)&dst[(size_t)r * KP + ch * 8] = *(const int4*)tmp;
  } else if (vb < NCVT + NTPJ) {
    const int b2 = vb - NCVT;
    const int j0 = (b2 % 48) * 32, p0 = (b2 / 48) * 32;
    const int tx = tid & 31, ty = tid >> 5;
    for (int i = ty; i < 32; i += 8)
      tile[i][tx] = projw[(size_t)(p0 + i) * (3 * H) + j0 + tx];
    __syncthreads();
    for (int i = ty; i < 32; i += 8)
      projT[(size_t)(j0 + i) * P + p0 + tx] = tile[tx][i];
  } else if (vb < NCVT + NTPJ + 2 * NTPF) {
    const int b3 = vb - NCVT - NTPJ;
    const bool isCtx = b3 >= NTPF;
    const int b4 = isCtx ? b3 - NTPF : b3;
    const float* W = isCtx ? ctxfcw : smfcw;
    float* WT = isCtx ? ctxfcwT : smfcwT;
    const int c0 = (b4 % 16) * 32, h0 = (b4 / 16) * 32;
    const int tx = tid & 31, ty = tid >> 5;
    for (int i = ty; i < 32; i += 8)
      tile[i][tx] = W[(size_t)(h0 + i) * C + c0 + tx];
    __syncthreads();
    for (int i = ty; i < 32; i += 8)
      WT[(size_t)(c0 + i) * H + h0 + tx] = tile[tx][i];
  } else {
    const int b5 = vb - NCVT - NTPJ - 2 * NTPF;
    const int qq = b5 * 4;            // 4 q-rows, same b (48 % 4 == 0)
    const int b = qq / Q;
    const float4* qp4 = (const float4*)(q + (size_t)qq * D);
    for (int i = tid; i < 300; i += 256) qrow4[i] = qp4[i];
    __syncthreads();
    const int sub = tid >> 6, lane = tid & 63;
    float qsq = 0.f;
    for (int i = lane; i < 75; i += 64) {
      float4 v = qrow4[sub * 75 + i];
      qsq += v.x * v.x + v.y * v.y + v.z * v.z + v.w * v.w;
    }
#pragma unroll
    for (int off2 = 32; off2; off2 >>= 1) qsq += __shfl_xor(qsq, off2);
    const float qn = sqrtf(qsq);
    if (lane < A) {
      const float4* ap4 = (const float4*)(a + ((size_t)b * A + lane) * D);
      float dot = 0.f, asq = 0.f;
      for (int i = 0; i < 75; ++i) {
        float4 av = ap4[i], qv = qrow4[sub * 75 + i];
        dot += qv.x * av.x + qv.y * av.y + qv.z * av.z + qv.w * av.w;
        asq += av.x * av.x + av.y * av.y + av.z * av.z + av.w * av.w;
      }
      cosm[(size_t)(qq + sub) * A + lane] = dot / fmaxf(qn * sqrtf(asq), EPS_COS);
    }
  }
}

// ---------------------------------------------------------------------------
// fused GEMM + pooling, sm & ctx in ONE dispatch (768 blocks, ctx first).
// 79.1 KB LDS -> 2 blocks/CU. S tile never touches global.
// ---------------------------------------------------------------------------
__global__ void __launch_bounds__(256)
fused_k(const short* __restrict__ qb, const short* __restrict__ ab,
        const short* __restrict__ smb, const short* __restrict__ ctxb,
        const float* __restrict__ cosm, const float* __restrict__ smbias,
        const float* __restrict__ ctxbias,
        float* __restrict__ pooled, float* __restrict__ pbar) {
  __shared__ float Sl[4][56][80];     // 71680 B, wave-private regions
  __shared__ short coslb[48][56];     // 5376 B (bf16 cos, ctx only)
  __shared__ float redf[512];         // 2048 B
  const int vb = blockIdx.x;
  const bool isCtx = vb < 256;
  const int v2 = isCtx ? vb : vb - 256;
  const int nb = v2 >> 3, cgi = v2 & 7;   // ctx: nb=b 0..31; sm: nb 0..63
  const int tid = threadIdx.x, lane = tid & 63, wv = tid >> 6;
  const int r16 = lane & 15, kq = lane >> 4;

  const short* X = isCtx ? ab + (size_t)nb * 48 * KP
      : ((nb < B) ? qb + (size_t)nb * 48 * KP : ab + (size_t)(nb - B) * 48 * KP);
  const short* Wm = isCtx ? ctxb : smb;
  const int gc0 = cgi * 320 + wv * 80;
  const short* Xw = X + (size_t)r16 * KP + kq * 8;
  const short* Wt = Wm + (size_t)(gc0 + r16) * KP + kq * 8;

  for (int i = lane; i < 640; i += 64) {  // zero-pad rows 0..3, 52..55
    const int rr = i / 80, cc2 = i % 80;
    Sl[wv][rr < 4 ? rr : rr + 48][cc2] = 0.f;
  }
  if (isCtx) {  // stage cos rows (bf16), zero-padded position axis
    for (int i = tid; i < 48 * 56; i += 256) {
      const int qi = i / 56, p4 = i % 56;
      const float cv = (p4 >= 4 && p4 < 52)
                     ? cosm[((size_t)nb * Q + qi) * A + p4 - 4] : 0.f;
      coslb[qi][p4] = f2bf(cv);
    }
  }

  f32x4 acc[3][5];
#pragma unroll
  for (int mi = 0; mi < 3; ++mi)
#pragma unroll
    for (int ni = 0; ni < 5; ++ni) acc[mi][ni] = f32x4{0.f, 0.f, 0.f, 0.f};
  int4 cA[3], cB[5];
#pragma unroll
  for (int i = 0; i < 3; ++i) cA[i] = *(const int4*)(Xw + i * 16 * KP);
#pragma unroll
  for (int i = 0; i < 5; ++i) cB[i] = *(const int4*)(Wt + i * 16 * KP);
#pragma unroll 1
  for (int ks = 0; ks < KP / 32; ++ks) {
    int4 nA[3], nB[5];
    if (ks < KP / 32 - 1) {
#pragma unroll
      for (int i = 0; i < 3; ++i) nA[i] = *(const int4*)(Xw + i * 16 * KP + (ks + 1) * 32);
#pragma unroll
      for (int i = 0; i < 5; ++i) nB[i] = *(const int4*)(Wt + i * 16 * KP + (ks + 1) * 32);
    }
#pragma unroll
    for (int mi = 0; mi < 3; ++mi)
#pragma unroll
      for (int ni = 0; ni < 5; ++ni)
        acc[mi][ni] = __builtin_amdgcn_mfma_f32_16x16x32_bf16(
            __builtin_bit_cast(short8, cA[mi]),
            __builtin_bit_cast(short8, cB[ni]), acc[mi][ni], 0, 0, 0);
    if (ks < KP / 32 - 1) {
#pragma unroll
      for (int i = 0; i < 3; ++i) cA[i] = nA[i];
#pragma unroll
      for (int i = 0; i < 5; ++i) cB[i] = nB[i];
    }
  }
#pragma unroll
  for (int mi = 0; mi < 3; ++mi)
#pragma unroll
    for (int ni = 0; ni < 5; ++ni)
#pragma unroll
      for (int r = 0; r < 4; ++r)
        Sl[wv][mi * 16 + kq * 4 + r + 4][ni * 16 + r16] = acc[mi][ni][r];
  __syncthreads();

  if (!isCtx) {
    const int ch = tid & 63, part = tid >> 6;
    const int w2 = ch >> 4, cl = (ch & 15) * 5;
    float best = -1e30f;
#pragma unroll
    for (int j = 0; j < 13; ++j) {
      const int l = part * 13 + j;
      const float z = Sl[w2][l + 0][cl + 0] + Sl[w2][l + 1][cl + 1]
                    + Sl[w2][l + 2][cl + 2] + Sl[w2][l + 3][cl + 3]
                    + Sl[w2][l + 4][cl + 4];
      best = fmaxf(best, z);
    }
    redf[part * 64 + ch] = best;
    __syncthreads();
    if (tid < 64) {
      const float m = fmaxf(fmaxf(redf[tid], redf[64 + tid]),
                            fmaxf(redf[128 + tid], redf[192 + tid]));
      pooled[(size_t)nb * C + cgi * 64 + tid] =
          fmaxf(m + smbias[cgi * 64 + tid], 0.f);
    }
  } else {
    const int clane = tid & 31, grp = tid >> 5;
    float best[2][6];
#pragma unroll
    for (int cc = 0; cc < 2; ++cc)
#pragma unroll
      for (int j = 0; j < 6; ++j) best[cc][j] = -1e30f;
    for (int ch13 = 0; ch13 < 13; ++ch13) {
      float cw[6][8];
#pragma unroll
      for (int j = 0; j < 6; ++j) {
        const short* crow = &coslb[grp * 6 + j][4 * ch13];
        const int2 w0 = *(const int2*)crow;
        const int2 w1 = *(const int2*)(crow + 4);
        cw[j][0] = __builtin_bit_cast(float, w0.x << 16);
        cw[j][1] = __builtin_bit_cast(float, (int)(w0.x & 0xffff0000));
        cw[j][2] = __builtin_bit_cast(float, w0.y << 16);
        cw[j][3] = __builtin_bit_cast(float, (int)(w0.y & 0xffff0000));
        cw[j][4] = __builtin_bit_cast(float, w1.x << 16);
        cw[j][5] = __builtin_bit_cast(float, (int)(w1.x & 0xffff0000));
        cw[j][6] = __builtin_bit_cast(float, w1.y << 16);
        cw[j][7] = __builtin_bit_cast(float, (int)(w1.y & 0xffff0000));
      }
#pragma unroll
      for (int cc = 0; cc < 2; ++cc) {
        const int ch = cc * 32 + clane;
        const int w2 = ch >> 4, cl = (ch & 15) * 5;
        float sk[4][5];
#pragma unroll
        for (int p = 0; p < 4; ++p)
#pragma unroll
          for (int k = 0; k < K; ++k)
            sk[p][k] = Sl[w2][4 * ch13 + p + k][cl + k];
#pragma unroll
        for (int p = 0; p < 4; ++p)
#pragma unroll
          for (int j = 0; j < 6; ++j) {
            float zv = 0.f;
#pragma unroll
            for (int k = 0; k < K; ++k) zv += cw[j][p + k] * sk[p][k];
            best[cc][j] = fmaxf(best[cc][j], zv);
          }
      }
    }
#pragma unroll
    for (int cc = 0; cc < 2; ++cc) {
      const float bc = ctxbias[cgi * 64 + cc * 32 + clane];
      float s = 0.f;
#pragma unroll
      for (int j = 0; j < 6; ++j) s += fmaxf(best[cc][j] + bc, 0.f);
      redf[cc * 256 + grp * 32 + clane] = s;
    }
    __syncthreads();
    if (tid < 64) {
      const int cc = tid >> 5, cl2 = tid & 31;
      float tot = 0.f;
#pragma unroll
      for (int g = 0; g < 8; ++g) tot += redf[cc * 256 + g * 32 + cl2];
      pbar[(size_t)nb * C + cgi * 64 + cc * 32 + cl2] = tot * (1.0f / Q);
    }
  }
}

// ---------------------------------------------------------------------------
// three FCs, coalesced via transposed weights.  grid 192 = (n,z,hc)
// ---------------------------------------------------------------------------
__global__ void fc_k(const float* __restrict__ pooled, const float* __restrict__ pbar,
                     const float* __restrict__ smfcwT, const float* __restrict__ smfcb,
                     const float* __restrict__ ctxfcwT, const float* __restrict__ ctxfcb,
                     float* __restrict__ acnn, float* __restrict__ bcnn,
                     float* __restrict__ attnf) {
  __shared__ float row[C];
  const int vb = blockIdx.x, tid = threadIdx.x;
  const int n = vb / 6, rem = vb % 6, z = rem >> 1, hc = rem & 1;
  const int h = hc * 256 + tid;
  const float* in = (z == 0) ? pooled + (size_t)n * C
                  : (z == 1) ? pooled + (size_t)(B + n) * C
                             : pbar + (size_t)n * C;
  const float* WT = (z == 2) ? ctxfcwT : smfcwT;
  const float* bs = (z == 2) ? ctxfcb : smfcb;
  float* outp = ((z == 0) ? acnn : (z == 1) ? bcnn : attnf) + (size_t)n * H;
  for (int c = tid; c < C; c += 256) row[c] = in[c];
  __syncthreads();
  float acc = bs[h];
  for (int c = 0; c < C; ++c) acc += row[c] * WT[(size_t)c * H + h];
  outp[h] = acc;
}

// ---------------------------------------------------------------------------
// proj -> comb directly.  grid 64 = (b, half); full 1536-j sum per thread.
// ---------------------------------------------------------------------------
__global__ void proj_k(const float* __restrict__ acnn, const float* __restrict__ bcnn,
                       const float* __restrict__ attnf, const float* __restrict__ WT,
                       const float* __restrict__ projb, float* __restrict__ comb) {
  __shared__ float cat[3 * H];
  const int b = blockIdx.x >> 1, half = blockIdx.x & 1;
  const int tid = threadIdx.x;
  const int p = half * 256 + tid;
  for (int j = tid; j < H; j += 256) {
    cat[j] = acnn[(size_t)b * H + j];
    cat[H + j] = bcnn[(size_t)b * H + j];
    cat[2 * H + j] = attnf[(size_t)b * H + j];
  }
  __syncthreads();
  float acc = projb[p];
  for (int j = 0; j < 3 * H; ++j) acc += cat[j] * WT[(size_t)j * P + p];
  comb[(size_t)b * P + p] = acc;
}

// ---------------------------------------------------------------------------
// batchnorm (train stats) + tanh.  grid 8 x 256; thread = (rg, p-lane).
// ---------------------------------------------------------------------------
__global__ void bn_k(const float* __restrict__ comb, const float* __restrict__ gamma,
                     const float* __restrict__ beta, float* __restrict__ t) {
  __shared__ float s1[256], s2[256];
  const int pl = threadIdx.x & 63, rg = threadIdx.x >> 6;
  const int p = blockIdx.x * 64 + pl;
  float v[8];
#pragma unroll
  for (int i = 0; i < 8; ++i) v[i] = comb[(size_t)(rg * 8 + i) * P + p];
  float a = 0.f;
#pragma unroll
  for (int i = 0; i < 8; ++i) a += v[i];
  s1[rg * 64 + pl] = a;
  __syncthreads();
  const float mu = (s1[pl] + s1[64 + pl] + s1[128 + pl] + s1[192 + pl]) * (1.0f / B);
  float b2 = 0.f;
#pragma unroll
  for (int i = 0; i < 8; ++i) { const float d = v[i] - mu; b2 += d * d; }
  s2[rg * 64 + pl] = b2;
  __syncthreads();
  const float var = (s2[pl] + s2[64 + pl] + s2[128 + pl] + s2[192 + pl]) * (1.0f / B);
  const float inv = rsqrtf(var + EPS_BN);
  const float g = gamma[p], be = beta[p];
#pragma unroll
  for (int i = 0; i < 8; ++i)
    t[(size_t)(rg * 8 + i) * P + p] = tanhf((v[i] - mu) * inv * g + be);
}

// ---------------------------------------------------------------------------
// final FC: logits[b,cl] = out_b[cl] + t[b,:] . out_w[cl,:]
// ---------------------------------------------------------------------------
__global__ void out_k(const float* __restrict__ t, const float* __restrict__ W,
                      const float* __restrict__ bias, float* __restrict__ out) {
  const int tid = threadIdx.x;  // 512
  const int o = tid >> 3, lane8 = tid & 7;
  const int bb = o >> 1, cl = o & 1;
  float acc = 0.f;
  for (int j = lane8; j < P; j += 8) acc += t[(size_t)bb * P + j] * W[cl * P + j];
#pragma unroll
  for (int off = 4; off; off >>= 1) acc += __shfl_down(acc, off);
  if (lane8 == 0) out[bb * NCLS + cl] = acc + bias[cl];
}

extern "C" void kernel_launch(void* const* d_in, const int* in_sizes, int n_in,
                              void* d_out, int out_size, void* d_ws, size_t ws_size,
                              hipStream_t stream) {
  const float* q       = (const float*)d_in[0];
  const float* a       = (const float*)d_in[1];
  const float* sm_w    = (const float*)d_in[2];
  const float* sm_b    = (const float*)d_in[3];
  const float* sm_fcw  = (const float*)d_in[4];
  const float* sm_fcb  = (const float*)d_in[5];
  const float* ctx_w   = (const float*)d_in[6];
  const float* ctx_b   = (const float*)d_in[7];
  const float* ctx_fcw = (const float*)d_in[8];
  const float* ctx_fcb = (const float*)d_in[9];
  const float* proj_w  = (const float*)d_in[10];
  const float* proj_b  = (const float*)d_in[11];
  const float* gamma   = (const float*)d_in[12];
  const float* beta    = (const float*)d_in[13];
  const float* out_w   = (const float*)d_in[14];
  const float* out_b   = (const float*)d_in[15];

  float* ws = (float*)d_ws;
  size_t off = 0;
  auto alloc = [&](size_t n) { float* p = ws + off; off += n; return p; };
  float* projT   = alloc((size_t)3 * H * P);
  float* smfcwT  = alloc((size_t)C * H);
  float* ctxfcwT = alloc((size_t)C * H);
  float* cosm    = alloc((size_t)B * Q * A);
  float* pooled  = alloc((size_t)2 * B * C);
  float* pbar    = alloc((size_t)B * C);
  float* acnn    = alloc((size_t)B * H);
  float* bcnn    = alloc((size_t)B * H);
  float* attnf   = alloc((size_t)B * H);
  float* comb    = alloc((size_t)B * P);
  float* tbuf    = alloc((size_t)B * P);
  short* qb      = (short*)alloc((size_t)M * KP / 2);
  short* ab      = (short*)alloc((size_t)M * KP / 2);
  short* smb2    = (short*)alloc((size_t)CK * KP / 2);
  short* ctxb2   = (short*)alloc((size_t)CK * KP / 2);

  prep_k<<<NPREP, 256, 0, stream>>>(q, a, sm_w, ctx_w, proj_w, sm_fcw, ctx_fcw,
                                    qb, ab, smb2, ctxb2, projT, smfcwT, ctxfcwT, cosm);
  fused_k<<<768, 256, 0, stream>>>(qb, ab, smb2, ctxb2, cosm, sm_b, ctx_b,
                                   pooled, pbar);
  fc_k<<<192, 256, 0, stream>>>(pooled, pbar, smfcwT, sm_fcb, ctxfcwT, ctx_fcb,
                                acnn, bcnn, attnf);
  proj_k<<<64, 256, 0, stream>>>(acnn, bcnn, attnf, projT, proj_b, comb);
  bn_k<<<8, 256, 0, stream>>>(comb, gamma, beta, tbuf);
  out_k<<<1, 512, 0, stream>>>(tbuf, out_w, out_b, (float*)d_out);
}

// Round 10
// 113.683 us; speedup vs baseline: 2.5858x; 1.2240x over previous
//
#include <hip/hip_runtime.h>
#include <math.h>
#include <stdint.h>

namespace {
constexpr int B = 32, Q = 48, A = 48, D = 300;
constexpr int C = 512, K = 5, H = 512, P = 512, NCLS = 2;
constexpr int CK = C * K;         // 2560
constexpr int M = B * Q;          // 1536
constexpr int KP = 320;           // K padded for bf16 MFMA
constexpr float EPS_COS = 1e-6f, EPS_BN = 1e-5f;
constexpr int NCVT = (2 * (M + CK) * 40) / 256;      // 1280 virtual blocks
constexpr int NTPJ = (3 * H / 32) * (P / 32);        // 768  (proj_w transpose)
constexpr int NTPF = (H / 32) * (C / 32);            // 256  (each fc weight)
constexpr int NCOS = M / 4;                          // 384
constexpr int NPREP = NCVT + NTPJ + 2 * NTPF + NCOS; // 2944
constexpr int NJ = 8;                                // proj j-chunks
}
using short8 = __attribute__((ext_vector_type(8))) short;
using f32x4  = __attribute__((ext_vector_type(4))) float;

__device__ inline short f2bf(float v) {
  uint32_t u = __builtin_bit_cast(uint32_t, v);
  return (short)((u + 0x7fffu + ((u >> 16) & 1u)) >> 16);  // RNE
}
__device__ inline float bf2f(short s) {
  uint32_t u = ((uint32_t)(uint16_t)s) << 16;
  return __builtin_bit_cast(float, u);
}

// ---------------------------------------------------------------------------
// prep: fp32->bf16 pad-to-320 | proj_w / fc_w transposes | cosine sim
// ---------------------------------------------------------------------------
__global__ void prep_k(const float* __restrict__ q, const float* __restrict__ a,
                       const float* __restrict__ smw, const float* __restrict__ ctxw,
                       const float* __restrict__ projw, const float* __restrict__ smfcw,
                       const float* __restrict__ ctxfcw,
                       short* __restrict__ qb, short* __restrict__ ab,
                       short* __restrict__ smb, short* __restrict__ ctxb,
                       float* __restrict__ projT, float* __restrict__ smfcwT,
                       float* __restrict__ ctxfcwT, float* __restrict__ cosm) {
  __shared__ float tile[32][33];
  __shared__ float4 qrow4[300];
  const int vb = blockIdx.x, tid = threadIdx.x;
  if (vb < NCVT) {
    const int idx = vb * 256 + tid;
    const int row = idx / 40, ch = idx - row * 40;
    const float* src; short* dst; int r;
    if (row < M)              { src = q;    dst = qb;   r = row; }
    else if (row < 2 * M)     { src = a;    dst = ab;   r = row - M; }
    else if (row < 2 * M + CK){ src = smw;  dst = smb;  r = row - 2 * M; }
    else                      { src = ctxw; dst = ctxb; r = row - 2 * M - CK; }
    short tmp[8];
#pragma unroll
    for (int e = 0; e < 8; ++e) {
      const int k = ch * 8 + e;
      tmp[e] = (k < D) ? f2bf(src[(size_t)r * D + k]) : (short)0;
    }
    *(int4*)&dst[(size_t)r * KP + ch * 8] = *(const int4*)tmp;
  } else if (vb < NCVT + NTPJ) {
    const int b2 = vb - NCVT;
    const int j0 = (b2 % 48) * 32, p0 = (b2 / 48) * 32;
    const int tx = tid & 31, ty = tid >> 5;
    for (int i = ty; i < 32; i += 8)
      tile[i][tx] = projw[(size_t)(p0 + i) * (3 * H) + j0 + tx];
    __syncthreads();
    for (int i = ty; i < 32; i += 8)
      projT[(size_t)(j0 + i) * P + p0 + tx] = tile[tx][i];
  } else if (vb < NCVT + NTPJ + 2 * NTPF) {
    const int b3 = vb - NCVT - NTPJ;
    const bool isCtx = b3 >= NTPF;
    const int b4 = isCtx ? b3 - NTPF : b3;
    const float* W = isCtx ? ctxfcw : smfcw;
    float* WT = isCtx ? ctxfcwT : smfcwT;
    const int c0 = (b4 % 16) * 32, h0 = (b4 / 16) * 32;
    const int tx = tid & 31, ty = tid >> 5;
    for (int i = ty; i < 32; i += 8)
      tile[i][tx] = W[(size_t)(h0 + i) * C + c0 + tx];
    __syncthreads();
    for (int i = ty; i < 32; i += 8)
      WT[(size_t)(c0 + i) * H + h0 + tx] = tile[tx][i];
  } else {
    const int b5 = vb - NCVT - NTPJ - 2 * NTPF;
    const int qq = b5 * 4;            // 4 q-rows, same b (48 % 4 == 0)
    const int b = qq / Q;
    const float4* qp4 = (const float4*)(q + (size_t)qq * D);
    for (int i = tid; i < 300; i += 256) qrow4[i] = qp4[i];
    __syncthreads();
    const int sub = tid >> 6, lane = tid & 63;
    float qsq = 0.f;
    for (int i = lane; i < 75; i += 64) {
      float4 v = qrow4[sub * 75 + i];
      qsq += v.x * v.x + v.y * v.y + v.z * v.z + v.w * v.w;
    }
#pragma unroll
    for (int off2 = 32; off2; off2 >>= 1) qsq += __shfl_xor(qsq, off2);
    const float qn = sqrtf(qsq);
    if (lane < A) {
      const float4* ap4 = (const float4*)(a + ((size_t)b * A + lane) * D);
      float dot = 0.f, asq = 0.f;
      for (int i = 0; i < 75; ++i) {
        float4 av = ap4[i], qv = qrow4[sub * 75 + i];
        dot += qv.x * av.x + qv.y * av.y + qv.z * av.z + qv.w * av.w;
        asq += av.x * av.x + av.y * av.y + av.z * av.z + av.w * av.w;
      }
      cosm[(size_t)(qq + sub) * A + lane] = dot / fmaxf(qn * sqrtf(asq), EPS_COS);
    }
  }
}

// ---------------------------------------------------------------------------
// fused GEMM + pooling, sm & ctx, ONE dispatch (768 blocks = 3/CU, ctx first)
// S tile in bf16 LDS: 48.6 KB total -> 3 blocks/CU.
// ---------------------------------------------------------------------------
__global__ void __launch_bounds__(256)
fused_k(const short* __restrict__ qb, const short* __restrict__ ab,
        const short* __restrict__ smb, const short* __restrict__ ctxb,
        const float* __restrict__ cosm, const float* __restrict__ smbias,
        const float* __restrict__ ctxbias,
        float* __restrict__ pooled, float* __restrict__ pbar) {
  __shared__ short Sl[4][56][80];     // 35840 B (bf16 S, wave-private regions)
  __shared__ float cosl[48][56];      // 10752 B (fp32 cos, ctx only)
  __shared__ float redf[512];         // 2048 B
  const int vb = blockIdx.x;
  const bool isCtx = vb < 256;
  const int v2 = isCtx ? vb : vb - 256;
  const int nb = v2 >> 3, cgi = v2 & 7;   // ctx: nb=b 0..31; sm: nb 0..63
  const int tid = threadIdx.x, lane = tid & 63, wv = tid >> 6;
  const int r16 = lane & 15, kq = lane >> 4;

  const short* X = isCtx ? ab + (size_t)nb * 48 * KP
      : ((nb < B) ? qb + (size_t)nb * 48 * KP : ab + (size_t)(nb - B) * 48 * KP);
  const short* Wm = isCtx ? ctxb : smb;
  const int gc0 = cgi * 320 + wv * 80;
  const short* Xw = X + (size_t)r16 * KP + kq * 8;
  const short* Wt = Wm + (size_t)(gc0 + r16) * KP + kq * 8;

  for (int i = lane; i < 640; i += 64) {  // zero-pad rows 0..3, 52..55
    const int rr = i / 80, cc2 = i % 80;
    Sl[wv][rr < 4 ? rr : rr + 48][cc2] = 0;
  }
  if (isCtx) {  // stage cos rows (fp32), zero-padded position axis
    for (int i = tid; i < 48 * 56; i += 256) {
      const int qi = i / 56, p4 = i % 56;
      cosl[qi][p4] = (p4 >= 4 && p4 < 52)
                   ? cosm[((size_t)nb * Q + qi) * A + p4 - 4] : 0.f;
    }
  }

  f32x4 acc[3][5];
#pragma unroll
  for (int mi = 0; mi < 3; ++mi)
#pragma unroll
    for (int ni = 0; ni < 5; ++ni) acc[mi][ni] = f32x4{0.f, 0.f, 0.f, 0.f};
  int4 cA[3], cB[5];
#pragma unroll
  for (int i = 0; i < 3; ++i) cA[i] = *(const int4*)(Xw + i * 16 * KP);
#pragma unroll
  for (int i = 0; i < 5; ++i) cB[i] = *(const int4*)(Wt + i * 16 * KP);
#pragma unroll 1
  for (int ks = 0; ks < KP / 32; ++ks) {
    int4 nA[3], nB[5];
    if (ks < KP / 32 - 1) {
#pragma unroll
      for (int i = 0; i < 3; ++i) nA[i] = *(const int4*)(Xw + i * 16 * KP + (ks + 1) * 32);
#pragma unroll
      for (int i = 0; i < 5; ++i) nB[i] = *(const int4*)(Wt + i * 16 * KP + (ks + 1) * 32);
    }
#pragma unroll
    for (int mi = 0; mi < 3; ++mi)
#pragma unroll
      for (int ni = 0; ni < 5; ++ni)
        acc[mi][ni] = __builtin_amdgcn_mfma_f32_16x16x32_bf16(
            __builtin_bit_cast(short8, cA[mi]),
            __builtin_bit_cast(short8, cB[ni]), acc[mi][ni], 0, 0, 0);
    if (ks < KP / 32 - 1) {
#pragma unroll
      for (int i = 0; i < 3; ++i) cA[i] = nA[i];
#pragma unroll
      for (int i = 0; i < 5; ++i) cB[i] = nB[i];
    }
  }
#pragma unroll
  for (int mi = 0; mi < 3; ++mi)
#pragma unroll
    for (int ni = 0; ni < 5; ++ni)
#pragma unroll
      for (int r = 0; r < 4; ++r)
        Sl[wv][mi * 16 + kq * 4 + r + 4][ni * 16 + r16] = f2bf(acc[mi][ni][r]);
  __syncthreads();

  if (!isCtx) {
    const int ch = tid & 63, part = tid >> 6;
    const int w2 = ch >> 4, cl = (ch & 15) * 5;
    float best = -1e30f;
#pragma unroll
    for (int j = 0; j < 13; ++j) {
      const int l = part * 13 + j;
      const float z = bf2f(Sl[w2][l + 0][cl + 0]) + bf2f(Sl[w2][l + 1][cl + 1])
                    + bf2f(Sl[w2][l + 2][cl + 2]) + bf2f(Sl[w2][l + 3][cl + 3])
                    + bf2f(Sl[w2][l + 4][cl + 4]);
      best = fmaxf(best, z);
    }
    redf[part * 64 + ch] = best;
    __syncthreads();
    if (tid < 64) {
      const float m = fmaxf(fmaxf(redf[tid], redf[64 + tid]),
                            fmaxf(redf[128 + tid], redf[192 + tid]));
      pooled[(size_t)nb * C + cgi * 64 + tid] =
          fmaxf(m + smbias[cgi * 64 + tid], 0.f);
    }
  } else {
    const int clane = tid & 31, grp = tid >> 5;
    float best[2][6];
#pragma unroll
    for (int cc = 0; cc < 2; ++cc)
#pragma unroll
      for (int j = 0; j < 6; ++j) best[cc][j] = -1e30f;
    for (int ch13 = 0; ch13 < 13; ++ch13) {
      float cw[6][8];
#pragma unroll
      for (int j = 0; j < 6; ++j) {
        const float4 a0 = *(const float4*)&cosl[grp * 6 + j][4 * ch13];
        const float4 a1 = *(const float4*)&cosl[grp * 6 + j][4 * ch13 + 4];
        cw[j][0] = a0.x; cw[j][1] = a0.y; cw[j][2] = a0.z; cw[j][3] = a0.w;
        cw[j][4] = a1.x; cw[j][5] = a1.y; cw[j][6] = a1.z; cw[j][7] = a1.w;
      }
#pragma unroll
      for (int cc = 0; cc < 2; ++cc) {
        const int ch = cc * 32 + clane;
        const int w2 = ch >> 4, cl = (ch & 15) * 5;
        float sk[4][5];
#pragma unroll
        for (int p = 0; p < 4; ++p)
#pragma unroll
          for (int k = 0; k < K; ++k)
            sk[p][k] = bf2f(Sl[w2][4 * ch13 + p + k][cl + k]);
#pragma unroll
        for (int p = 0; p < 4; ++p)
#pragma unroll
          for (int j = 0; j < 6; ++j) {
            float zv = 0.f;
#pragma unroll
            for (int k = 0; k < K; ++k) zv += cw[j][p + k] * sk[p][k];
            best[cc][j] = fmaxf(best[cc][j], zv);
          }
      }
    }
#pragma unroll
    for (int cc = 0; cc < 2; ++cc) {
      const float bc = ctxbias[cgi * 64 + cc * 32 + clane];
      float s = 0.f;
#pragma unroll
      for (int j = 0; j < 6; ++j) s += fmaxf(best[cc][j] + bc, 0.f);
      redf[cc * 256 + grp * 32 + clane] = s;
    }
    __syncthreads();
    if (tid < 64) {
      const int cc = tid >> 5, cl2 = tid & 31;
      float tot = 0.f;
#pragma unroll
      for (int g = 0; g < 8; ++g) tot += redf[cc * 256 + g * 32 + cl2];
      pbar[(size_t)nb * C + cgi * 64 + cc * 32 + cl2] = tot * (1.0f / Q);
    }
  }
}

// ---------------------------------------------------------------------------
// three FCs, coalesced via transposed weights.  grid 192 = (n,z,hc)
// ---------------------------------------------------------------------------
__global__ void fc_k(const float* __restrict__ pooled, const float* __restrict__ pbar,
                     const float* __restrict__ smfcwT, const float* __restrict__ smfcb,
                     const float* __restrict__ ctxfcwT, const float* __restrict__ ctxfcb,
                     float* __restrict__ acnn, float* __restrict__ bcnn,
                     float* __restrict__ attnf) {
  __shared__ float row[C];
  const int vb = blockIdx.x, tid = threadIdx.x;
  const int n = vb / 6, rem = vb % 6, z = rem >> 1, hc = rem & 1;
  const int h = hc * 256 + tid;
  const float* in = (z == 0) ? pooled + (size_t)n * C
                  : (z == 1) ? pooled + (size_t)(B + n) * C
                             : pbar + (size_t)n * C;
  const float* WT = (z == 2) ? ctxfcwT : smfcwT;
  const float* bs = (z == 2) ? ctxfcb : smfcb;
  float* outp = ((z == 0) ? acnn : (z == 1) ? bcnn : attnf) + (size_t)n * H;
  for (int c = tid; c < C; c += 256) row[c] = in[c];
  __syncthreads();
  float acc = bs[h];
  for (int c = 0; c < C; ++c) acc += row[c] * WT[(size_t)c * H + h];
  outp[h] = acc;
}

// ---------------------------------------------------------------------------
// proj, split 8-way over j: partial[g][b][p] = sum_{j in chunk} cat[b,j]*WT[j,p]
// ---------------------------------------------------------------------------
__global__ void proj_k(const float* __restrict__ acnn, const float* __restrict__ bcnn,
                       const float* __restrict__ attnf, const float* __restrict__ WT,
                       float* __restrict__ partial) {
  __shared__ float cs[192];
  const int b = blockIdx.x, g = blockIdx.y, tid = threadIdx.x;
  const int js = g * 192;
  if (tid < 192) {
    const int j = js + tid;
    float v;
    if (j < H)          v = acnn[(size_t)b * H + j];
    else if (j < 2 * H) v = bcnn[(size_t)b * H + j - H];
    else                v = attnf[(size_t)b * H + j - 2 * H];
    cs[tid] = v;
  }
  __syncthreads();
  float a0 = 0.f, a1 = 0.f;
  for (int j = 0; j < 192; ++j) {
    const float c = cs[j];
    a0 += c * WT[(size_t)(js + j) * P + tid];
    a1 += c * WT[(size_t)(js + j) * P + tid + 256];
  }
  partial[((size_t)g * B + b) * P + tid] = a0;
  partial[((size_t)g * B + b) * P + tid + 256] = a1;
}

// ---------------------------------------------------------------------------
// bnmid: sum proj partials; batch stats over B; tanh -> t.
// ---------------------------------------------------------------------------
__global__ void bnmid_k(const float* __restrict__ partial, const float* __restrict__ proj_b,
                        const float* __restrict__ gamma, const float* __restrict__ beta,
                        float* __restrict__ t) {
  __shared__ float s1[256], s2[256];
  const int pl = threadIdx.x & 63, rg = threadIdx.x >> 6;
  const int p = blockIdx.x * 64 + pl;
  const float pb = proj_b[p];
  float v[8];
#pragma unroll
  for (int i = 0; i < 8; ++i) {
    const int r = rg * 8 + i;
    float s = pb;
#pragma unroll
    for (int g = 0; g < NJ; ++g) s += partial[((size_t)g * B + r) * P + p];
    v[i] = s;
  }
  float a = 0.f;
#pragma unroll
  for (int i = 0; i < 8; ++i) a += v[i];
  s1[rg * 64 + pl] = a;
  __syncthreads();
  const float mu = (s1[pl] + s1[64 + pl] + s1[128 + pl] + s1[192 + pl]) * (1.0f / B);
  float b2 = 0.f;
#pragma unroll
  for (int i = 0; i < 8; ++i) { const float d = v[i] - mu; b2 += d * d; }
  s2[rg * 64 + pl] = b2;
  __syncthreads();
  const float var = (s2[pl] + s2[64 + pl] + s2[128 + pl] + s2[192 + pl]) * (1.0f / B);
  const float inv = rsqrtf(var + EPS_BN);
  const float g = gamma[p], be = beta[p];
#pragma unroll
  for (int i = 0; i < 8; ++i)
    t[(size_t)(rg * 8 + i) * P + p] = tanhf((v[i] - mu) * inv * g + be);
}

// ---------------------------------------------------------------------------
// final FC: logits[b,cl] = out_b[cl] + t[b,:] . out_w[cl,:]
// ---------------------------------------------------------------------------
__global__ void out_k(const float* __restrict__ t, const float* __restrict__ W,
                      const float* __restrict__ bias, float* __restrict__ out) {
  const int tid = threadIdx.x;  // 512
  const int o = tid >> 3, lane8 = tid & 7;
  const int bb = o >> 1, cl = o & 1;
  float acc = 0.f;
  for (int j = lane8; j < P; j += 8) acc += t[(size_t)bb * P + j] * W[cl * P + j];
#pragma unroll
  for (int off = 4; off; off >>= 1) acc += __shfl_down(acc, off);
  if (lane8 == 0) out[bb * NCLS + cl] = acc + bias[cl];
}

extern "C" void kernel_launch(void* const* d_in, const int* in_sizes, int n_in,
                              void* d_out, int out_size, void* d_ws, size_t ws_size,
                              hipStream_t stream) {
  const float* q       = (const float*)d_in[0];
  const float* a       = (const float*)d_in[1];
  const float* sm_w    = (const float*)d_in[2];
  const float* sm_b    = (const float*)d_in[3];
  const float* sm_fcw  = (const float*)d_in[4];
  const float* sm_fcb  = (const float*)d_in[5];
  const float* ctx_w   = (const float*)d_in[6];
  const float* ctx_b   = (const float*)d_in[7];
  const float* ctx_fcw = (const float*)d_in[8];
  const float* ctx_fcb = (const float*)d_in[9];
  const float* proj_w  = (const float*)d_in[10];
  const float* proj_b  = (const float*)d_in[11];
  const float* gamma   = (const float*)d_in[12];
  const float* beta    = (const float*)d_in[13];
  const float* out_w   = (const float*)d_in[14];
  const float* out_b   = (const float*)d_in[15];

  float* ws = (float*)d_ws;
  size_t off = 0;
  auto alloc = [&](size_t n) { float* p = ws + off; off += n; return p; };
  float* projT   = alloc((size_t)3 * H * P);
  float* smfcwT  = alloc((size_t)C * H);
  float* ctxfcwT = alloc((size_t)C * H);
  float* cosm    = alloc((size_t)B * Q * A);
  float* pooled  = alloc((size_t)2 * B * C);
  float* pbar    = alloc((size_t)B * C);
  float* acnn    = alloc((size_t)B * H);
  float* bcnn    = alloc((size_t)B * H);
  float* attnf   = alloc((size_t)B * H);
  float* partial = alloc((size_t)NJ * B * P);
  float* tbuf    = alloc((size_t)B * P);
  short* qb      = (short*)alloc((size_t)M * KP / 2);
  short* ab      = (short*)alloc((size_t)M * KP / 2);
  short* smb2    = (short*)alloc((size_t)CK * KP / 2);
  short* ctxb2   = (short*)alloc((size_t)CK * KP / 2);

  prep_k<<<NPREP, 256, 0, stream>>>(q, a, sm_w, ctx_w, proj_w, sm_fcw, ctx_fcw,
                                    qb, ab, smb2, ctxb2, projT, smfcwT, ctxfcwT, cosm);
  fused_k<<<768, 256, 0, stream>>>(qb, ab, smb2, ctxb2, cosm, sm_b, ctx_b,
                                   pooled, pbar);
  fc_k<<<192, 256, 0, stream>>>(pooled, pbar, smfcwT, sm_fcb, ctxfcwT, ctx_fcb,
                                acnn, bcnn, attnf);
  proj_k<<<dim3(B, NJ), 256, 0, stream>>>(acnn, bcnn, attnf, projT, partial);
  bnmid_k<<<P / 64, 256, 0, stream>>>(partial, proj_b, gamma, beta, tbuf);
  out_k<<<1, 512, 0, stream>>>(tbuf, out_w, out_b, (float*)d_out);
}

// Round 11
// 89.888 us; speedup vs baseline: 3.2703x; 1.2647x over previous
//
#include <hip/hip_runtime.h>
#include <math.h>
#include <stdint.h>

namespace {
constexpr int B = 32, Q = 48, A = 48, D = 300;
constexpr int C = 512, K = 5, H = 512, P = 512, NCLS = 2;
constexpr int CK = C * K;         // 2560
constexpr int M = B * Q;          // 1536
constexpr int KP = 320;           // K padded for bf16 MFMA
constexpr float EPS_COS = 1e-6f, EPS_BN = 1e-5f;
constexpr int NPAN = 96 + 96 + 160 + 160;   // 512 16-row panels to convert
constexpr int NCOS = M / 4;                 // 384
constexpr int NJ = 8;                       // proj j-chunks
constexpr int PSZ = 40 * 16 * 8;            // 5120 shorts per panel
}
using short8 = __attribute__((ext_vector_type(8))) short;
using f32x4  = __attribute__((ext_vector_type(4))) float;

__device__ inline short f2bf(float v) {
  uint32_t u = __builtin_bit_cast(uint32_t, v);
  return (short)((u + 0x7fffu + ((u >> 16) & 1u)) >> 16);  // RNE
}
__device__ inline float bf2f(short s) {
  uint32_t u = ((uint32_t)(uint16_t)s) << 16;
  return __builtin_bit_cast(float, u);
}

// ---------------------------------------------------------------------------
// prep: [0,512) fragment-major bf16 panel convert | [512,896) cosine sim
// Panel layout: X'[((p*40 + k8)*16 + r)*8] -> wave fragment loads are 1KB
// contiguous in fused_k.
// ---------------------------------------------------------------------------
__global__ void prep_k(const float* __restrict__ q, const float* __restrict__ a,
                       const float* __restrict__ smw, const float* __restrict__ ctxw,
                       short* __restrict__ qb, short* __restrict__ ab,
                       short* __restrict__ smb, short* __restrict__ ctxb,
                       float* __restrict__ cosm) {
  __shared__ float4 qrow4[300];
  const int vb = blockIdx.x, tid = threadIdx.x;
  if (vb < NPAN) {
    const float* src; short* dst; int pl;
    if (vb < 96)       { src = q;    dst = qb;   pl = vb; }
    else if (vb < 192) { src = a;    dst = ab;   pl = vb - 96; }
    else if (vb < 352) { src = smw;  dst = smb;  pl = vb - 192; }
    else               { src = ctxw; dst = ctxb; pl = vb - 352; }
    const int row0 = pl * 16;
    for (int it = tid; it < 640; it += 256) {
      const int k8 = it >> 4, r = it & 15;
      short tmp[8];
#pragma unroll
      for (int e = 0; e < 8; ++e) {
        const int k = k8 * 8 + e;
        tmp[e] = (k < D) ? f2bf(src[(size_t)(row0 + r) * D + k]) : (short)0;
      }
      *(int4*)&dst[(size_t)pl * PSZ + (size_t)k8 * 128 + r * 8] = *(const int4*)tmp;
    }
  } else {
    const int b5 = vb - NPAN;
    const int qq = b5 * 4;            // 4 q-rows, same b (48 % 4 == 0)
    const int b = qq / Q;
    const float4* qp4 = (const float4*)(q + (size_t)qq * D);
    for (int i = tid; i < 300; i += 256) qrow4[i] = qp4[i];
    __syncthreads();
    const int sub = tid >> 6, lane = tid & 63;
    float qsq = 0.f;
    for (int i = lane; i < 75; i += 64) {
      float4 v = qrow4[sub * 75 + i];
      qsq += v.x * v.x + v.y * v.y + v.z * v.z + v.w * v.w;
    }
#pragma unroll
    for (int off2 = 32; off2; off2 >>= 1) qsq += __shfl_xor(qsq, off2);
    const float qn = sqrtf(qsq);
    if (lane < A) {
      const float4* ap4 = (const float4*)(a + ((size_t)b * A + lane) * D);
      float dot = 0.f, asq = 0.f;
      for (int i = 0; i < 75; ++i) {
        float4 av = ap4[i], qv = qrow4[sub * 75 + i];
        dot += qv.x * av.x + qv.y * av.y + qv.z * av.z + qv.w * av.w;
        asq += av.x * av.x + av.y * av.y + av.z * av.z + av.w * av.w;
      }
      cosm[(size_t)(qq + sub) * A + lane] = dot / fmaxf(qn * sqrtf(asq), EPS_COS);
    }
  }
}

// ---------------------------------------------------------------------------
// fused: [0,256) ctx GEMM+pool | [256,768) sm GEMM+pool | [768,2048) weight
// transposes (fill idle CUs during ctx tail).
// GEMM: coalesced fragment-major loads, fp32 S in padded LDS [4][56][81],
// bf16 cos.  80000 B LDS -> 2 blocks/CU.
// ---------------------------------------------------------------------------
__global__ void __launch_bounds__(256)
fused_k(const short* __restrict__ qb, const short* __restrict__ ab,
        const short* __restrict__ smb, const short* __restrict__ ctxb,
        const float* __restrict__ cosm, const float* __restrict__ smbias,
        const float* __restrict__ ctxbias,
        const float* __restrict__ projw, const float* __restrict__ smfcw,
        const float* __restrict__ ctxfcw,
        float* __restrict__ projT, float* __restrict__ smfcwT,
        float* __restrict__ ctxfcwT,
        float* __restrict__ pooled, float* __restrict__ pbar) {
  __shared__ __align__(16) char Lraw[80000];
  const int vb = blockIdx.x, tid = threadIdx.x;

  if (vb >= 768) {  // ---------------- transpose blocks ----------------
    float (*tile)[33] = (float (*)[33])Lraw;
    const int vb2 = vb - 768;
    const int tx = tid & 31, ty = tid >> 5;
    if (vb2 < 768) {  // projT
      const int j0 = (vb2 % 48) * 32, p0 = (vb2 / 48) * 32;
      for (int i = ty; i < 32; i += 8)
        tile[i][tx] = projw[(size_t)(p0 + i) * (3 * H) + j0 + tx];
      __syncthreads();
      for (int i = ty; i < 32; i += 8)
        projT[(size_t)(j0 + i) * P + p0 + tx] = tile[tx][i];
    } else {
      const int b3 = vb2 - 768;
      const bool isC = b3 >= 256;
      const int b4 = isC ? b3 - 256 : b3;
      const float* W = isC ? ctxfcw : smfcw;
      float* WT = isC ? ctxfcwT : smfcwT;
      const int c0 = (b4 % 16) * 32, h0 = (b4 / 16) * 32;
      for (int i = ty; i < 32; i += 8)
        tile[i][tx] = W[(size_t)(h0 + i) * C + c0 + tx];
      __syncthreads();
      for (int i = ty; i < 32; i += 8)
        WT[(size_t)(c0 + i) * H + h0 + tx] = tile[tx][i];
    }
    return;
  }

  // ---------------- GEMM + pool blocks ----------------
  float (*Sl)[56][81] = (float (*)[56][81])Lraw;          // 72576 B
  short (*coslb)[56]  = (short (*)[56])(Lraw + 72576);    // 5376 B
  float* redf         = (float*)(Lraw + 77952);           // 2048 B
  const bool isCtx = vb < 256;
  const int v2 = isCtx ? vb : vb - 256;
  const int nb = v2 >> 3, cgi = v2 & 7;   // ctx: nb=b 0..31; sm: nb 0..63
  const int lane = tid & 63, wv = tid >> 6;
  const int r16 = lane & 15, kq = lane >> 4;

  const short* Xp = isCtx ? ab : ((nb < B) ? qb : ab);
  const int xp0 = (isCtx ? nb : ((nb < B) ? nb : nb - B)) * 3;
  const short* Wp = isCtx ? ctxb : smb;
  const int wp0 = cgi * 20 + wv * 5;
  const short* Xw = Xp + (size_t)xp0 * PSZ + kq * 128 + r16 * 8;
  const short* Ww = Wp + (size_t)wp0 * PSZ + kq * 128 + r16 * 8;

  for (int i = lane; i < 640; i += 64) {  // zero-pad rows 0..3, 52..55
    const int rr = i / 80, cc2 = i % 80;
    Sl[wv][rr < 4 ? rr : rr + 48][cc2] = 0.f;
  }
  if (isCtx) {  // stage cos rows (bf16), zero-padded position axis
    for (int i = tid; i < 48 * 56; i += 256) {
      const int qi = i / 56, p4 = i % 56;
      const float cv = (p4 >= 4 && p4 < 52)
                     ? cosm[((size_t)nb * Q + qi) * A + p4 - 4] : 0.f;
      coslb[qi][p4] = f2bf(cv);
    }
  }

  f32x4 acc[3][5];
#pragma unroll
  for (int mi = 0; mi < 3; ++mi)
#pragma unroll
    for (int ni = 0; ni < 5; ++ni) acc[mi][ni] = f32x4{0.f, 0.f, 0.f, 0.f};
  int4 cA[3], cB[5];
#pragma unroll
  for (int i = 0; i < 3; ++i) cA[i] = *(const int4*)(Xw + (size_t)i * PSZ);
#pragma unroll
  for (int i = 0; i < 5; ++i) cB[i] = *(const int4*)(Ww + (size_t)i * PSZ);
#pragma unroll 1
  for (int ks = 0; ks < KP / 32; ++ks) {
    int4 nA[3], nB[5];
    if (ks < KP / 32 - 1) {
#pragma unroll
      for (int i = 0; i < 3; ++i) nA[i] = *(const int4*)(Xw + (size_t)i * PSZ + (ks + 1) * 512);
#pragma unroll
      for (int i = 0; i < 5; ++i) nB[i] = *(const int4*)(Ww + (size_t)i * PSZ + (ks + 1) * 512);
    }
#pragma unroll
    for (int mi = 0; mi < 3; ++mi)
#pragma unroll
      for (int ni = 0; ni < 5; ++ni)
        acc[mi][ni] = __builtin_amdgcn_mfma_f32_16x16x32_bf16(
            __builtin_bit_cast(short8, cA[mi]),
            __builtin_bit_cast(short8, cB[ni]), acc[mi][ni], 0, 0, 0);
    if (ks < KP / 32 - 1) {
#pragma unroll
      for (int i = 0; i < 3; ++i) cA[i] = nA[i];
#pragma unroll
      for (int i = 0; i < 5; ++i) cB[i] = nB[i];
    }
  }
#pragma unroll
  for (int mi = 0; mi < 3; ++mi)
#pragma unroll
    for (int ni = 0; ni < 5; ++ni)
#pragma unroll
      for (int r = 0; r < 4; ++r)
        Sl[wv][mi * 16 + kq * 4 + r + 4][ni * 16 + r16] = acc[mi][ni][r];
  __syncthreads();

  if (!isCtx) {
    const int ch = tid & 63, part = tid >> 6;
    const int w2 = ch >> 4, cl = (ch & 15) * 5;
    float best = -1e30f;
#pragma unroll
    for (int j = 0; j < 13; ++j) {
      const int l = part * 13 + j;
      const float z = Sl[w2][l + 0][cl + 0] + Sl[w2][l + 1][cl + 1]
                    + Sl[w2][l + 2][cl + 2] + Sl[w2][l + 3][cl + 3]
                    + Sl[w2][l + 4][cl + 4];
      best = fmaxf(best, z);
    }
    redf[part * 64 + ch] = best;
    __syncthreads();
    if (tid < 64) {
      const float m = fmaxf(fmaxf(redf[tid], redf[64 + tid]),
                            fmaxf(redf[128 + tid], redf[192 + tid]));
      pooled[(size_t)nb * C + cgi * 64 + tid] =
          fmaxf(m + smbias[cgi * 64 + tid], 0.f);
    }
  } else {
    const int clane = tid & 31, grp = tid >> 5;
    float best[2][6];
#pragma unroll
    for (int cc = 0; cc < 2; ++cc)
#pragma unroll
      for (int j = 0; j < 6; ++j) best[cc][j] = -1e30f;
    for (int ch13 = 0; ch13 < 13; ++ch13) {
      float cw[6][8];
#pragma unroll
      for (int j = 0; j < 6; ++j) {
        const short* crow = &coslb[grp * 6 + j][4 * ch13];
        const int2 w0 = *(const int2*)crow;
        const int2 w1 = *(const int2*)(crow + 4);
        cw[j][0] = __builtin_bit_cast(float, w0.x << 16);
        cw[j][1] = __builtin_bit_cast(float, (int)(w0.x & 0xffff0000));
        cw[j][2] = __builtin_bit_cast(float, w0.y << 16);
        cw[j][3] = __builtin_bit_cast(float, (int)(w0.y & 0xffff0000));
        cw[j][4] = __builtin_bit_cast(float, w1.x << 16);
        cw[j][5] = __builtin_bit_cast(float, (int)(w1.x & 0xffff0000));
        cw[j][6] = __builtin_bit_cast(float, w1.y << 16);
        cw[j][7] = __builtin_bit_cast(float, (int)(w1.y & 0xffff0000));
      }
#pragma unroll
      for (int cc = 0; cc < 2; ++cc) {
        const int ch = cc * 32 + clane;
        const int w2 = ch >> 4, cl = (ch & 15) * 5;
        float sk[4][5];
#pragma unroll
        for (int p = 0; p < 4; ++p)
#pragma unroll
          for (int k = 0; k < K; ++k)
            sk[p][k] = Sl[w2][4 * ch13 + p + k][cl + k];
#pragma unroll
        for (int p = 0; p < 4; ++p)
#pragma unroll
          for (int j = 0; j < 6; ++j) {
            float zv = 0.f;
#pragma unroll
            for (int k = 0; k < K; ++k) zv += cw[j][p + k] * sk[p][k];
            best[cc][j] = fmaxf(best[cc][j], zv);
          }
      }
    }
#pragma unroll
    for (int cc = 0; cc < 2; ++cc) {
      const float bc = ctxbias[cgi * 64 + cc * 32 + clane];
      float s = 0.f;
#pragma unroll
      for (int j = 0; j < 6; ++j) s += fmaxf(best[cc][j] + bc, 0.f);
      redf[cc * 256 + grp * 32 + clane] = s;
    }
    __syncthreads();
    if (tid < 64) {
      const int cc = tid >> 5, cl2 = tid & 31;
      float tot = 0.f;
#pragma unroll
      for (int g = 0; g < 8; ++g) tot += redf[cc * 256 + g * 32 + cl2];
      pbar[(size_t)nb * C + cgi * 64 + cc * 32 + cl2] = tot * (1.0f / Q);
    }
  }
}

// ---------------------------------------------------------------------------
// three FCs, coalesced via transposed weights.  grid 192 = (n,z,hc)
// ---------------------------------------------------------------------------
__global__ void fc_k(const float* __restrict__ pooled, const float* __restrict__ pbar,
                     const float* __restrict__ smfcwT, const float* __restrict__ smfcb,
                     const float* __restrict__ ctxfcwT, const float* __restrict__ ctxfcb,
                     float* __restrict__ acnn, float* __restrict__ bcnn,
                     float* __restrict__ attnf) {
  __shared__ float row[C];
  const int vb = blockIdx.x, tid = threadIdx.x;
  const int n = vb / 6, rem = vb % 6, z = rem >> 1, hc = rem & 1;
  const int h = hc * 256 + tid;
  const float* in = (z == 0) ? pooled + (size_t)n * C
                  : (z == 1) ? pooled + (size_t)(B + n) * C
                             : pbar + (size_t)n * C;
  const float* WT = (z == 2) ? ctxfcwT : smfcwT;
  const float* bs = (z == 2) ? ctxfcb : smfcb;
  float* outp = ((z == 0) ? acnn : (z == 1) ? bcnn : attnf) + (size_t)n * H;
  for (int c = tid; c < C; c += 256) row[c] = in[c];
  __syncthreads();
  float acc = bs[h];
  for (int c = 0; c < C; ++c) acc += row[c] * WT[(size_t)c * H + h];
  outp[h] = acc;
}

// ---------------------------------------------------------------------------
// proj, split 8-way over j
// ---------------------------------------------------------------------------
__global__ void proj_k(const float* __restrict__ acnn, const float* __restrict__ bcnn,
                       const float* __restrict__ attnf, const float* __restrict__ WT,
                       float* __restrict__ partial) {
  __shared__ float cs[192];
  const int b = blockIdx.x, g = blockIdx.y, tid = threadIdx.x;
  const int js = g * 192;
  if (tid < 192) {
    const int j = js + tid;
    float v;
    if (j < H)          v = acnn[(size_t)b * H + j];
    else if (j < 2 * H) v = bcnn[(size_t)b * H + j - H];
    else                v = attnf[(size_t)b * H + j - 2 * H];
    cs[tid] = v;
  }
  __syncthreads();
  float a0 = 0.f, a1 = 0.f;
  for (int j = 0; j < 192; ++j) {
    const float c = cs[j];
    a0 += c * WT[(size_t)(js + j) * P + tid];
    a1 += c * WT[(size_t)(js + j) * P + tid + 256];
  }
  partial[((size_t)g * B + b) * P + tid] = a0;
  partial[((size_t)g * B + b) * P + tid + 256] = a1;
}

// ---------------------------------------------------------------------------
// bnmid: sum proj partials; batch stats over B; tanh -> t.
// ---------------------------------------------------------------------------
__global__ void bnmid_k(const float* __restrict__ partial, const float* __restrict__ proj_b,
                        const float* __restrict__ gamma, const float* __restrict__ beta,
                        float* __restrict__ t) {
  __shared__ float s1[256], s2[256];
  const int pl = threadIdx.x & 63, rg = threadIdx.x >> 6;
  const int p = blockIdx.x * 64 + pl;
  const float pb = proj_b[p];
  float v[8];
#pragma unroll
  for (int i = 0; i < 8; ++i) {
    const int r = rg * 8 + i;
    float s = pb;
#pragma unroll
    for (int g = 0; g < NJ; ++g) s += partial[((size_t)g * B + r) * P + p];
    v[i] = s;
  }
  float a = 0.f;
#pragma unroll
  for (int i = 0; i < 8; ++i) a += v[i];
  s1[rg * 64 + pl] = a;
  __syncthreads();
  const float mu = (s1[pl] + s1[64 + pl] + s1[128 + pl] + s1[192 + pl]) * (1.0f / B);
  float b2 = 0.f;
#pragma unroll
  for (int i = 0; i < 8; ++i) { const float d = v[i] - mu; b2 += d * d; }
  s2[rg * 64 + pl] = b2;
  __syncthreads();
  const float var = (s2[pl] + s2[64 + pl] + s2[128 + pl] + s2[192 + pl]) * (1.0f / B);
  const float inv = rsqrtf(var + EPS_BN);
  const float g = gamma[p], be = beta[p];
#pragma unroll
  for (int i = 0; i < 8; ++i)
    t[(size_t)(rg * 8 + i) * P + p] = tanhf((v[i] - mu) * inv * g + be);
}

// ---------------------------------------------------------------------------
// final FC
// ---------------------------------------------------------------------------
__global__ void out_k(const float* __restrict__ t, const float* __restrict__ W,
                      const float* __restrict__ bias, float* __restrict__ out) {
  const int tid = threadIdx.x;  // 512
  const int o = tid >> 3, lane8 = tid & 7;
  const int bb = o >> 1, cl = o & 1;
  float acc = 0.f;
  for (int j = lane8; j < P; j += 8) acc += t[(size_t)bb * P + j] * W[cl * P + j];
#pragma unroll
  for (int off = 4; off; off >>= 1) acc += __shfl_down(acc, off);
  if (lane8 == 0) out[bb * NCLS + cl] = acc + bias[cl];
}

extern "C" void kernel_launch(void* const* d_in, const int* in_sizes, int n_in,
                              void* d_out, int out_size, void* d_ws, size_t ws_size,
                              hipStream_t stream) {
  const float* q       = (const float*)d_in[0];
  const float* a       = (const float*)d_in[1];
  const float* sm_w    = (const float*)d_in[2];
  const float* sm_b    = (const float*)d_in[3];
  const float* sm_fcw  = (const float*)d_in[4];
  const float* sm_fcb  = (const float*)d_in[5];
  const float* ctx_w   = (const float*)d_in[6];
  const float* ctx_b   = (const float*)d_in[7];
  const float* ctx_fcw = (const float*)d_in[8];
  const float* ctx_fcb = (const float*)d_in[9];
  const float* proj_w  = (const float*)d_in[10];
  const float* proj_b  = (const float*)d_in[11];
  const float* gamma   = (const float*)d_in[12];
  const float* beta    = (const float*)d_in[13];
  const float* out_w   = (const float*)d_in[14];
  const float* out_b   = (const float*)d_in[15];

  float* ws = (float*)d_ws;
  size_t off = 0;
  auto alloc = [&](size_t n) { float* p = ws + off; off += n; return p; };
  float* projT   = alloc((size_t)3 * H * P);
  float* smfcwT  = alloc((size_t)C * H);
  float* ctxfcwT = alloc((size_t)C * H);
  float* cosm    = alloc((size_t)B * Q * A);
  float* pooled  = alloc((size_t)2 * B * C);
  float* pbar    = alloc((size_t)B * C);
  float* acnn    = alloc((size_t)B * H);
  float* bcnn    = alloc((size_t)B * H);
  float* attnf   = alloc((size_t)B * H);
  float* partial = alloc((size_t)NJ * B * P);
  float* tbuf    = alloc((size_t)B * P);
  short* qb      = (short*)alloc((size_t)M * KP / 2);
  short* ab      = (short*)alloc((size_t)M * KP / 2);
  short* smb2    = (short*)alloc((size_t)CK * KP / 2);
  short* ctxb2   = (short*)alloc((size_t)CK * KP / 2);

  prep_k<<<NPAN + NCOS, 256, 0, stream>>>(q, a, sm_w, ctx_w, qb, ab, smb2, ctxb2, cosm);
  fused_k<<<2048, 256, 0, stream>>>(qb, ab, smb2, ctxb2, cosm, sm_b, ctx_b,
                                    proj_w, sm_fcw, ctx_fcw, projT, smfcwT, ctxfcwT,
                                    pooled, pbar);
  fc_k<<<192, 256, 0, stream>>>(pooled, pbar, smfcwT, sm_fcb, ctxfcwT, ctx_fcb,
                                acnn, bcnn, attnf);
  proj_k<<<dim3(B, NJ), 256, 0, stream>>>(acnn, bcnn, attnf, projT, partial);
  bnmid_k<<<P / 64, 256, 0, stream>>>(partial, proj_b, gamma, beta, tbuf);
  out_k<<<1, 512, 0, stream>>>(tbuf, out_w, out_b, (float*)d_out);
}

// Round 12
// 83.298 us; speedup vs baseline: 3.5290x; 1.0791x over previous
//
#include <hip/hip_runtime.h>
#include <math.h>
#include <stdint.h>

namespace {
constexpr int B = 32, Q = 48, A = 48, D = 300;
constexpr int C = 512, K = 5, H = 512, P = 512, NCLS = 2;
constexpr int CK = C * K;         // 2560
constexpr int M = B * Q;          // 1536
constexpr int KP = 320;           // K padded for bf16 MFMA
constexpr float EPS_COS = 1e-6f, EPS_BN = 1e-5f;
constexpr int NPAN = 96 + 96 + 160 + 160;   // 512 16-row panels to convert
constexpr int NCOS = M / 4;                 // 384
constexpr int NJ = 8;                       // proj j-chunks
constexpr int PSZ = 40 * 16 * 8;            // 5120 shorts per panel
}
using short8 = __attribute__((ext_vector_type(8))) short;
using f32x4  = __attribute__((ext_vector_type(4))) float;

__device__ inline short f2bf(float v) {
  uint32_t u = __builtin_bit_cast(uint32_t, v);
  return (short)((u + 0x7fffu + ((u >> 16) & 1u)) >> 16);  // RNE
}

// ---------------------------------------------------------------------------
// prep: [0,512) fragment-major bf16 panel convert (LDS-staged, coalesced both
// sides) | [512,896) cosine sim
// ---------------------------------------------------------------------------
__global__ void prep_k(const float* __restrict__ q, const float* __restrict__ a,
                       const float* __restrict__ smw, const float* __restrict__ ctxw,
                       short* __restrict__ qb, short* __restrict__ ab,
                       short* __restrict__ smb, short* __restrict__ ctxb,
                       float* __restrict__ cosm) {
  __shared__ float sa[16 * 300];    // 19.2 KB panel stage
  __shared__ float4 qrow4[300];
  const int vb = blockIdx.x, tid = threadIdx.x;
  if (vb < NPAN) {
    const float* src; short* dst; int pl;
    if (vb < 96)       { src = q;    dst = qb;   pl = vb; }
    else if (vb < 192) { src = a;    dst = ab;   pl = vb - 96; }
    else if (vb < 352) { src = smw;  dst = smb;  pl = vb - 192; }
    else               { src = ctxw; dst = ctxb; pl = vb - 352; }
    const int row0 = pl * 16;
    // coalesced float4 reads -> LDS
    for (int i = tid; i < 1200; i += 256) {
      const int r = i / 75, c4 = i - r * 75;
      const float4 v = *(const float4*)&src[(size_t)(row0 + r) * D + c4 * 4];
      *(float4*)&sa[r * 300 + c4 * 4] = v;
    }
    __syncthreads();
    // fragment-major bf16 writes (consecutive tid -> consecutive 16B)
    for (int it = tid; it < 640; it += 256) {
      const int k8 = it >> 4, r = it & 15;
      short tmp[8];
#pragma unroll
      for (int e = 0; e < 8; ++e) {
        const int k = k8 * 8 + e;
        tmp[e] = (k < D) ? f2bf(sa[r * 300 + k]) : (short)0;
      }
      *(int4*)&dst[(size_t)pl * PSZ + (size_t)k8 * 128 + r * 8] = *(const int4*)tmp;
    }
  } else {
    const int b5 = vb - NPAN;
    const int qq = b5 * 4;            // 4 q-rows, same b (48 % 4 == 0)
    const int b = qq / Q;
    const float4* qp4 = (const float4*)(q + (size_t)qq * D);
    for (int i = tid; i < 300; i += 256) qrow4[i] = qp4[i];
    __syncthreads();
    const int sub = tid >> 6, lane = tid & 63;
    float qsq = 0.f;
    for (int i = lane; i < 75; i += 64) {
      float4 v = qrow4[sub * 75 + i];
      qsq += v.x * v.x + v.y * v.y + v.z * v.z + v.w * v.w;
    }
#pragma unroll
    for (int off2 = 32; off2; off2 >>= 1) qsq += __shfl_xor(qsq, off2);
    const float qn = sqrtf(qsq);
    if (lane < A) {
      const float4* ap4 = (const float4*)(a + ((size_t)b * A + lane) * D);
      float dot = 0.f, asq = 0.f;
      for (int i = 0; i < 75; ++i) {
        float4 av = ap4[i], qv = qrow4[sub * 75 + i];
        dot += qv.x * av.x + qv.y * av.y + qv.z * av.z + qv.w * av.w;
        asq += av.x * av.x + av.y * av.y + av.z * av.z + av.w * av.w;
      }
      cosm[(size_t)(qq + sub) * A + lane] = dot / fmaxf(qn * sqrtf(asq), EPS_COS);
    }
  }
}

// ---------------------------------------------------------------------------
// fused: [0,256) ctx GEMM+pool | [256,768) sm GEMM+pool | [768,2048) weight
// transposes.  Coalesced fragment-major loads, 2-deep prefetch, fp32 S in
// padded LDS [4][56][81], bf16 cos.  80000 B LDS -> 2 blocks/CU.
// ---------------------------------------------------------------------------
__global__ void __launch_bounds__(256)
fused_k(const short* __restrict__ qb, const short* __restrict__ ab,
        const short* __restrict__ smb, const short* __restrict__ ctxb,
        const float* __restrict__ cosm, const float* __restrict__ smbias,
        const float* __restrict__ ctxbias,
        const float* __restrict__ projw, const float* __restrict__ smfcw,
        const float* __restrict__ ctxfcw,
        float* __restrict__ projT, float* __restrict__ smfcwT,
        float* __restrict__ ctxfcwT,
        float* __restrict__ pooled, float* __restrict__ pbar) {
  __shared__ __align__(16) char Lraw[80000];
  const int vb = blockIdx.x, tid = threadIdx.x;

  if (vb >= 768) {  // ---------------- transpose blocks ----------------
    float (*tile)[33] = (float (*)[33])Lraw;
    const int vb2 = vb - 768;
    const int tx = tid & 31, ty = tid >> 5;
    if (vb2 < 768) {  // projT
      const int j0 = (vb2 % 48) * 32, p0 = (vb2 / 48) * 32;
      for (int i = ty; i < 32; i += 8)
        tile[i][tx] = projw[(size_t)(p0 + i) * (3 * H) + j0 + tx];
      __syncthreads();
      for (int i = ty; i < 32; i += 8)
        projT[(size_t)(j0 + i) * P + p0 + tx] = tile[tx][i];
    } else {
      const int b3 = vb2 - 768;
      const bool isC = b3 >= 256;
      const int b4 = isC ? b3 - 256 : b3;
      const float* W = isC ? ctxfcw : smfcw;
      float* WT = isC ? ctxfcwT : smfcwT;
      const int c0 = (b4 % 16) * 32, h0 = (b4 / 16) * 32;
      for (int i = ty; i < 32; i += 8)
        tile[i][tx] = W[(size_t)(h0 + i) * C + c0 + tx];
      __syncthreads();
      for (int i = ty; i < 32; i += 8)
        WT[(size_t)(c0 + i) * H + h0 + tx] = tile[tx][i];
    }
    return;
  }

  // ---------------- GEMM + pool blocks ----------------
  float (*Sl)[56][81] = (float (*)[56][81])Lraw;          // 72576 B
  short (*coslb)[56]  = (short (*)[56])(Lraw + 72576);    // 5376 B
  float* redf         = (float*)(Lraw + 77952);           // 2048 B
  const bool isCtx = vb < 256;
  const int v2 = isCtx ? vb : vb - 256;
  const int nb = v2 >> 3, cgi = v2 & 7;   // ctx: nb=b 0..31; sm: nb 0..63
  const int lane = tid & 63, wv = tid >> 6;
  const int r16 = lane & 15, kq = lane >> 4;

  const short* Xp = isCtx ? ab : ((nb < B) ? qb : ab);
  const int xp0 = (isCtx ? nb : ((nb < B) ? nb : nb - B)) * 3;
  const short* Wp = isCtx ? ctxb : smb;
  const int wp0 = cgi * 20 + wv * 5;
  const short* Xw = Xp + (size_t)xp0 * PSZ + kq * 128 + r16 * 8;
  const short* Ww = Wp + (size_t)wp0 * PSZ + kq * 128 + r16 * 8;

  for (int i = lane; i < 640; i += 64) {  // zero-pad rows 0..3, 52..55
    const int rr = i / 80, cc2 = i % 80;
    Sl[wv][rr < 4 ? rr : rr + 48][cc2] = 0.f;
  }
  if (isCtx) {  // stage cos rows (bf16), zero-padded position axis
    for (int i = tid; i < 48 * 56; i += 256) {
      const int qi = i / 56, p4 = i % 56;
      const float cv = (p4 >= 4 && p4 < 52)
                     ? cosm[((size_t)nb * Q + qi) * A + p4 - 4] : 0.f;
      coslb[qi][p4] = f2bf(cv);
    }
  }

  f32x4 acc[3][5];
#pragma unroll
  for (int mi = 0; mi < 3; ++mi)
#pragma unroll
    for (int ni = 0; ni < 5; ++ni) acc[mi][ni] = f32x4{0.f, 0.f, 0.f, 0.f};

  int4 cA0[3], cB0[5], cA1[3], cB1[5];
  auto issue = [&](int ks, int4* pA, int4* pB) {
#pragma unroll
    for (int i = 0; i < 3; ++i) pA[i] = *(const int4*)(Xw + (size_t)i * PSZ + ks * 512);
#pragma unroll
    for (int i = 0; i < 5; ++i) pB[i] = *(const int4*)(Ww + (size_t)i * PSZ + ks * 512);
  };
  auto domfma = [&](const int4* pA, const int4* pB) {
#pragma unroll
    for (int mi = 0; mi < 3; ++mi)
#pragma unroll
      for (int ni = 0; ni < 5; ++ni)
        acc[mi][ni] = __builtin_amdgcn_mfma_f32_16x16x32_bf16(
            __builtin_bit_cast(short8, pA[mi]),
            __builtin_bit_cast(short8, pB[ni]), acc[mi][ni], 0, 0, 0);
  };

  issue(0, cA0, cB0);
  issue(1, cA1, cB1);
#pragma unroll
  for (int ks2 = 0; ks2 < 5; ++ks2) {
    const int ks = 2 * ks2;
    domfma(cA0, cB0);
    if (ks + 2 < 10) issue(ks + 2, cA0, cB0);
    domfma(cA1, cB1);
    if (ks + 3 < 10) issue(ks + 3, cA1, cB1);
  }
#pragma unroll
  for (int mi = 0; mi < 3; ++mi)
#pragma unroll
    for (int ni = 0; ni < 5; ++ni)
#pragma unroll
      for (int r = 0; r < 4; ++r)
        Sl[wv][mi * 16 + kq * 4 + r + 4][ni * 16 + r16] = acc[mi][ni][r];
  __syncthreads();

  if (!isCtx) {
    const int ch = tid & 63, part = tid >> 6;
    const int w2 = ch >> 4, cl = (ch & 15) * 5;
    float best = -1e30f;
#pragma unroll
    for (int j = 0; j < 13; ++j) {
      const int l = part * 13 + j;
      const float z = Sl[w2][l + 0][cl + 0] + Sl[w2][l + 1][cl + 1]
                    + Sl[w2][l + 2][cl + 2] + Sl[w2][l + 3][cl + 3]
                    + Sl[w2][l + 4][cl + 4];
      best = fmaxf(best, z);
    }
    redf[part * 64 + ch] = best;
    __syncthreads();
    if (tid < 64) {
      const float m = fmaxf(fmaxf(redf[tid], redf[64 + tid]),
                            fmaxf(redf[128 + tid], redf[192 + tid]));
      pooled[(size_t)nb * C + cgi * 64 + tid] =
          fmaxf(m + smbias[cgi * 64 + tid], 0.f);
    }
  } else {
    const int clane = tid & 31, grp = tid >> 5;
    float best[2][6];
#pragma unroll
    for (int cc = 0; cc < 2; ++cc)
#pragma unroll
      for (int j = 0; j < 6; ++j) best[cc][j] = -1e30f;
    for (int ch13 = 0; ch13 < 13; ++ch13) {
      float cw[6][8];
#pragma unroll
      for (int j = 0; j < 6; ++j) {
        const short* crow = &coslb[grp * 6 + j][4 * ch13];
        const int2 w0 = *(const int2*)crow;
        const int2 w1 = *(const int2*)(crow + 4);
        cw[j][0] = __builtin_bit_cast(float, w0.x << 16);
        cw[j][1] = __builtin_bit_cast(float, (int)(w0.x & 0xffff0000));
        cw[j][2] = __builtin_bit_cast(float, w0.y << 16);
        cw[j][3] = __builtin_bit_cast(float, (int)(w0.y & 0xffff0000));
        cw[j][4] = __builtin_bit_cast(float, w1.x << 16);
        cw[j][5] = __builtin_bit_cast(float, (int)(w1.x & 0xffff0000));
        cw[j][6] = __builtin_bit_cast(float, w1.y << 16);
        cw[j][7] = __builtin_bit_cast(float, (int)(w1.y & 0xffff0000));
      }
#pragma unroll
      for (int cc = 0; cc < 2; ++cc) {
        const int ch = cc * 32 + clane;
        const int w2 = ch >> 4, cl = (ch & 15) * 5;
        float sk[4][5];
#pragma unroll
        for (int p = 0; p < 4; ++p)
#pragma unroll
          for (int k = 0; k < K; ++k)
            sk[p][k] = Sl[w2][4 * ch13 + p + k][cl + k];
#pragma unroll
        for (int p = 0; p < 4; ++p)
#pragma unroll
          for (int j = 0; j < 6; ++j) {
            float zv = 0.f;
#pragma unroll
            for (int k = 0; k < K; ++k) zv += cw[j][p + k] * sk[p][k];
            best[cc][j] = fmaxf(best[cc][j], zv);
          }
      }
    }
#pragma unroll
    for (int cc = 0; cc < 2; ++cc) {
      const float bc = ctxbias[cgi * 64 + cc * 32 + clane];
      float s = 0.f;
#pragma unroll
      for (int j = 0; j < 6; ++j) s += fmaxf(best[cc][j] + bc, 0.f);
      redf[cc * 256 + grp * 32 + clane] = s;
    }
    __syncthreads();
    if (tid < 64) {
      const int cc = tid >> 5, cl2 = tid & 31;
      float tot = 0.f;
#pragma unroll
      for (int g = 0; g < 8; ++g) tot += redf[cc * 256 + g * 32 + cl2];
      pbar[(size_t)nb * C + cgi * 64 + cc * 32 + cl2] = tot * (1.0f / Q);
    }
  }
}

// ---------------------------------------------------------------------------
// projfc: recompute the 192 FC outputs this block needs, then proj partial.
// grid (B, NJ).  partial[g][b][p] = sum_{j in chunk} cat[b,j]*projT[j,p]
// (cat includes FC bias; bnmid adds projb.)
// ---------------------------------------------------------------------------
__global__ void projfc_k(const float* __restrict__ pooled, const float* __restrict__ pbar,
                         const float* __restrict__ smfcwT, const float* __restrict__ smfcb,
                         const float* __restrict__ ctxfcwT, const float* __restrict__ ctxfcb,
                         const float* __restrict__ projT, float* __restrict__ partial) {
  __shared__ float rows[3 * C];   // [q-pooled | a-pooled | pbar] for this b
  __shared__ float cs[192];
  const int b = blockIdx.x, g = blockIdx.y, tid = threadIdx.x;
  for (int i = tid; i < C; i += 256) {
    rows[i] = pooled[(size_t)b * C + i];
    rows[C + i] = pooled[(size_t)(B + b) * C + i];
    rows[2 * C + i] = pbar[(size_t)b * C + i];
  }
  __syncthreads();
  if (tid < 192) {
    const int j = g * 192 + tid;
    const int seg = j >> 9, h = j & 511;
    const float* WT = (seg == 2) ? ctxfcwT : smfcwT;
    const float* in = rows + seg * C;
    float acc = (seg == 2) ? ctxfcb[h] : smfcb[h];
    for (int c = 0; c < C; ++c) acc += in[c] * WT[(size_t)c * H + h];
    cs[tid] = acc;
  }
  __syncthreads();
  const int js = g * 192;
  float a0 = 0.f, a1 = 0.f;
  for (int j = 0; j < 192; ++j) {
    const float c = cs[j];
    a0 += c * projT[(size_t)(js + j) * P + tid];
    a1 += c * projT[(size_t)(js + j) * P + tid + 256];
  }
  partial[((size_t)g * B + b) * P + tid] = a0;
  partial[((size_t)g * B + b) * P + tid + 256] = a1;
}

// ---------------------------------------------------------------------------
// bnmid: sum proj partials; batch stats over B; tanh -> t.
// ---------------------------------------------------------------------------
__global__ void bnmid_k(const float* __restrict__ partial, const float* __restrict__ proj_b,
                        const float* __restrict__ gamma, const float* __restrict__ beta,
                        float* __restrict__ t) {
  __shared__ float s1[256], s2[256];
  const int pl = threadIdx.x & 63, rg = threadIdx.x >> 6;
  const int p = blockIdx.x * 64 + pl;
  const float pb = proj_b[p];
  float v[8];
#pragma unroll
  for (int i = 0; i < 8; ++i) {
    const int r = rg * 8 + i;
    float s = pb;
#pragma unroll
    for (int g = 0; g < NJ; ++g) s += partial[((size_t)g * B + r) * P + p];
    v[i] = s;
  }
  float a = 0.f;
#pragma unroll
  for (int i = 0; i < 8; ++i) a += v[i];
  s1[rg * 64 + pl] = a;
  __syncthreads();
  const float mu = (s1[pl] + s1[64 + pl] + s1[128 + pl] + s1[192 + pl]) * (1.0f / B);
  float b2 = 0.f;
#pragma unroll
  for (int i = 0; i < 8; ++i) { const float d = v[i] - mu; b2 += d * d; }
  s2[rg * 64 + pl] = b2;
  __syncthreads();
  const float var = (s2[pl] + s2[64 + pl] + s2[128 + pl] + s2[192 + pl]) * (1.0f / B);
  const float inv = rsqrtf(var + EPS_BN);
  const float g = gamma[p], be = beta[p];
#pragma unroll
  for (int i = 0; i < 8; ++i)
    t[(size_t)(rg * 8 + i) * P + p] = tanhf((v[i] - mu) * inv * g + be);
}

// ---------------------------------------------------------------------------
// final FC
// ---------------------------------------------------------------------------
__global__ void out_k(const float* __restrict__ t, const float* __restrict__ W,
                      const float* __restrict__ bias, float* __restrict__ out) {
  const int tid = threadIdx.x;  // 512
  const int o = tid >> 3, lane8 = tid & 7;
  const int bb = o >> 1, cl = o & 1;
  float acc = 0.f;
  for (int j = lane8; j < P; j += 8) acc += t[(size_t)bb * P + j] * W[cl * P + j];
#pragma unroll
  for (int off = 4; off; off >>= 1) acc += __shfl_down(acc, off);
  if (lane8 == 0) out[bb * NCLS + cl] = acc + bias[cl];
}

extern "C" void kernel_launch(void* const* d_in, const int* in_sizes, int n_in,
                              void* d_out, int out_size, void* d_ws, size_t ws_size,
                              hipStream_t stream) {
  const float* q       = (const float*)d_in[0];
  const float* a       = (const float*)d_in[1];
  const float* sm_w    = (const float*)d_in[2];
  const float* sm_b    = (const float*)d_in[3];
  const float* sm_fcw  = (const float*)d_in[4];
  const float* sm_fcb  = (const float*)d_in[5];
  const float* ctx_w   = (const float*)d_in[6];
  const float* ctx_b   = (const float*)d_in[7];
  const float* ctx_fcw = (const float*)d_in[8];
  const float* ctx_fcb = (const float*)d_in[9];
  const float* proj_w  = (const float*)d_in[10];
  const float* proj_b  = (const float*)d_in[11];
  const float* gamma   = (const float*)d_in[12];
  const float* beta    = (const float*)d_in[13];
  const float* out_w   = (const float*)d_in[14];
  const float* out_b   = (const float*)d_in[15];

  float* ws = (float*)d_ws;
  size_t off = 0;
  auto alloc = [&](size_t n) { float* p = ws + off; off += n; return p; };
  float* projT   = alloc((size_t)3 * H * P);
  float* smfcwT  = alloc((size_t)C * H);
  float* ctxfcwT = alloc((size_t)C * H);
  float* cosm    = alloc((size_t)B * Q * A);
  float* pooled  = alloc((size_t)2 * B * C);
  float* pbar    = alloc((size_t)B * C);
  float* partial = alloc((size_t)NJ * B * P);
  float* tbuf    = alloc((size_t)B * P);
  short* qb      = (short*)alloc((size_t)M * KP / 2);
  short* ab      = (short*)alloc((size_t)M * KP / 2);
  short* smb2    = (short*)alloc((size_t)CK * KP / 2);
  short* ctxb2   = (short*)alloc((size_t)CK * KP / 2);

  prep_k<<<NPAN + NCOS, 256, 0, stream>>>(q, a, sm_w, ctx_w, qb, ab, smb2, ctxb2, cosm);
  fused_k<<<2048, 256, 0, stream>>>(qb, ab, smb2, ctxb2, cosm, sm_b, ctx_b,
                                    proj_w, sm_fcw, ctx_fcw, projT, smfcwT, ctxfcwT,
                                    pooled, pbar);
  projfc_k<<<dim3(B, NJ), 256, 0, stream>>>(pooled, pbar, smfcwT, sm_fcb,
                                            ctxfcwT, ctx_fcb, projT, partial);
  bnmid_k<<<P / 64, 256, 0, stream>>>(partial, proj_b, gamma, beta, tbuf);
  out_k<<<1, 512, 0, stream>>>(tbuf, out_w, out_b, (float*)d_out);
}